// Round 11
// baseline (275.031 us; speedup 1.0000x reference)
//
#include <hip/hip_runtime.h>
#include <hip/hip_bf16.h>
#include <math.h>

typedef short short8 __attribute__((ext_vector_type(8)));
typedef short short4v __attribute__((ext_vector_type(4)));
typedef float f32x4 __attribute__((ext_vector_type(4)));
typedef __hip_bfloat16 bf16;

// problem constants
#define KN 10
#define KC 512
#define KHW 1600
#define KH 40
#define KOC 128
#define KPW 42   // padded spatial (40+2)
#define KM 1280  // stacked M: 9 conv taps * 128 + 128 shortcut

// direct global->LDS DMA, 16B per lane. LDS dest must be wave-uniform base + lane*16.
__device__ __forceinline__ void gload16(const void* g, void* l) {
  __builtin_amdgcn_global_load_lds(
      (const __attribute__((address_space(1))) unsigned int*)g,
      (__attribute__((address_space(3))) unsigned int*)l, 16, 0, 0);
}

// ---------------- block reduction helpers (fp64) ----------------
__device__ __forceinline__ double blockReduceSumD(double v) {
  __shared__ double tmpS[8];
  int lane = threadIdx.x & 63, wv = threadIdx.x >> 6;
  #pragma unroll
  for (int o = 32; o > 0; o >>= 1) v += __shfl_down(v, o);
  if (lane == 0) tmpS[wv] = v;
  __syncthreads();
  if (threadIdx.x == 0) {
    int nw = (blockDim.x + 63) >> 6;
    double s = 0;
    for (int i = 0; i < nw; i++) s += tmpS[i];
    tmpS[0] = s;
  }
  __syncthreads();
  double r = tmpS[0];
  __syncthreads();
  return r;
}

__device__ __forceinline__ double blockReduceMinD(double v) {
  __shared__ double tmpMn[8];
  int lane = threadIdx.x & 63, wv = threadIdx.x >> 6;
  #pragma unroll
  for (int o = 32; o > 0; o >>= 1) v = fmin(v, __shfl_down(v, o));
  if (lane == 0) tmpMn[wv] = v;
  __syncthreads();
  if (threadIdx.x == 0) {
    int nw = (blockDim.x + 63) >> 6;
    double s = tmpMn[0];
    for (int i = 1; i < nw; i++) s = fmin(s, tmpMn[i]);
    tmpMn[0] = s;
  }
  __syncthreads();
  double r = tmpMn[0];
  __syncthreads();
  return r;
}

__device__ __forceinline__ double blockReduceMaxD(double v) {
  __shared__ double tmpMx[8];
  int lane = threadIdx.x & 63, wv = threadIdx.x >> 6;
  #pragma unroll
  for (int o = 32; o > 0; o >>= 1) v = fmax(v, __shfl_down(v, o));
  if (lane == 0) tmpMx[wv] = v;
  __syncthreads();
  if (threadIdx.x == 0) {
    int nw = (blockDim.x + 63) >> 6;
    double s = tmpMx[0];
    for (int i = 1; i < nw; i++) s = fmax(s, tmpMx[i]);
    tmpMx[0] = s;
  }
  __syncthreads();
  double r = tmpMx[0];
  __syncthreads();
  return r;
}

// ---------------- small chain (fp64 for argsort stability) ----------------

// 16 channel-slices of 32: 1008 blocks
__global__ void k_rnormp(const float* __restrict__ feats, double* __restrict__ ps) {
  int t = blockIdx.x * 256 + threadIdx.x;
  if (t >= KN * KHW) return;
  int ci = blockIdx.y;
  int n = t / KHW, k = t % KHW;
  const float* p = feats + (size_t)n * KC * KHW + (size_t)ci * 32 * KHW + k;
  double s = 0.0;
  #pragma unroll
  for (int c = 0; c < 32; ++c) { double v = p[(size_t)c * KHW]; s += v * v; }
  ps[(size_t)ci * KN * KHW + t] = s;
}

__global__ void k_rnormc(const double* __restrict__ ps, double* __restrict__ rnorm) {
  int t = blockIdx.x * 256 + threadIdx.x;
  if (t >= KN * KHW) return;
  double s = 0;
  #pragma unroll
  for (int ci = 0; ci < 16; ci++) s += ps[(size_t)ci * KN * KHW + t];
  double nn = sqrt(s);
  if (nn < 1e-12) nn = 1e-12;
  rnorm[t] = 1.0 / nn;
}

// NFT[n,k,c] = bf16(feats[n,c,k] * rnorm[n,k]); also emits SIV pre-partials
__global__ void k_nft(const float* __restrict__ feats, const double* __restrict__ rnorm,
                      const float* __restrict__ sism, bf16* __restrict__ NFT,
                      double* __restrict__ vpp) {
  __shared__ float T[32][33];
  int n = blockIdx.z, k0 = blockIdx.x * 32, c0 = blockIdx.y * 32;
  int tx = threadIdx.x, ty = threadIdx.y;
  const float* fb = feats + ((size_t)n * KC + c0) * KHW + k0;
  #pragma unroll
  for (int ii = 0; ii < 4; ii++) {
    int cl = ty * 4 + ii;
    T[cl][tx] = fb[(size_t)cl * KHW + tx];
  }
  __syncthreads();
  bf16* ob = NFT + ((size_t)n * KHW + k0) * KC + c0;
  #pragma unroll
  for (int ii = 0; ii < 4; ii++) {
    int kl = ty * 4 + ii;
    float r = (float)rnorm[n * KHW + k0 + kl];
    ob[(size_t)kl * KC + tx] = __float2bfloat16(T[tx][kl] * r);
  }
  double rs = rnorm[n * KHW + k0 + tx] * (double)sism[n * KHW + k0 + tx];
  #pragma unroll
  for (int ii = 0; ii < 4; ii++) {
    int cl = ty * 4 + ii;
    double v = (double)T[cl][tx] * rs;
    #pragma unroll
    for (int o = 16; o > 0; o >>= 1) v += __shfl_down(v, o, 32);
    if (tx == 0) vpp[((size_t)n * KC + c0 + cl) * 50 + k0 / 32] = v;
  }
}

__global__ void k_sivnorm2(const double* __restrict__ vpp, double* __restrict__ SIV) {
  int n = blockIdx.x, c = threadIdx.x;   // 512 threads
  const double* p = vpp + ((size_t)n * KC + c) * 50;
  double acc = 0;
  #pragma unroll 5
  for (int j = 0; j < 50; j++) acc += p[j];
  acc /= (double)KHW;
  double s2 = blockReduceSumD(acc * acc);
  double nn = sqrt(s2);
  if (nn < 1e-12) nn = 1e-12;
  SIV[n * KC + c] = acc / nn;
}

// 16 channel-slices of 32: 1120 blocks
__global__ void k_cmP(const float* __restrict__ feats, const double* __restrict__ SIV,
                      double* __restrict__ cmp) {
  __shared__ double sv[KN][32];
  int kc = blockIdx.x, ci = blockIdx.y, n = blockIdx.z;
  for (int t = threadIdx.x; t < KN * 32; t += 256) {
    int m = t / 32, c = t % 32;
    sv[m][c] = SIV[m * KC + ci * 32 + c];
  }
  __syncthreads();
  int k = kc * 256 + threadIdx.x;
  if (k >= KHW) return;
  const float* f = feats + ((size_t)n * KC + ci * 32) * KHW + k;
  double acc[KN];
  #pragma unroll
  for (int m = 0; m < KN; m++) acc[m] = 0.0;
  for (int c = 0; c < 32; ++c) {
    double fv = f[(size_t)c * KHW];
    #pragma unroll
    for (int m = 0; m < KN; m++) acc[m] += fv * sv[m][c];
  }
  const size_t str = (size_t)KN * KN * KHW;
  #pragma unroll
  for (int m = 0; m < KN; m++)
    cmp[(size_t)ci * str + ((size_t)n * KN + m) * KHW + k] = acc[m];
}

// fused cmB + cmnorm
__global__ void k_cmBN(const double* __restrict__ cmp, const double* __restrict__ rnorm,
                       double* __restrict__ cm) {
  int b = blockIdx.x;                       // 100 = n*KN + m
  int n = b / KN;
  const size_t str = (size_t)KN * KN * KHW;
  const size_t rb = (size_t)b * KHW;
  double v[4];
  int cnt = 0;
  double ss = 0;
  for (int k = threadIdx.x; k < KHW; k += 512) {
    double s = 0;
    #pragma unroll
    for (int ci = 0; ci < 16; ci++) s += cmp[ci * str + rb + k];
    s *= rnorm[n * KHW + k];
    v[cnt++] = s;
    ss += s * s;
  }
  ss = blockReduceSumD(ss);
  double nn = sqrt(ss);
  if (nn < 1e-12) nn = 1e-12;
  double rn = 1.0 / nn;
  cnt = 0;
  for (int k = threadIdx.x; k < KHW; k += 512) cm[rb + k] = v[cnt++] * rn;
}

__global__ void k_st(const double* __restrict__ cm, double* __restrict__ tbuf) {
  int b = blockIdx.x;
  int n = b / KN, m = b % KN;
  const double* base = cm + (size_t)n * KN * KHW;
  double acc = 0;
  for (int k = threadIdx.x; k < KHW; k += 256) {
    double S = 0;
    #pragma unroll
    for (int mm = 0; mm < KN; mm++) S += base[(size_t)mm * KHW + k];
    acc += base[(size_t)m * KHW + k] * S;
  }
  acc = blockReduceSumD(acc);
  if (threadIdx.x == 0) tbuf[b] = acc;
}

__global__ void k_csa(const double* __restrict__ cm, const double* __restrict__ tbuf,
                      double* __restrict__ CSAd, float* __restrict__ CSAf) {
  __shared__ double w[KN];
  int n = blockIdx.x, tid = threadIdx.x;
  if (tid == 0) {
    double v[KN], mx = -1e300;
    #pragma unroll
    for (int m = 0; m < KN; m++) { v[m] = tbuf[n * KN + m]; mx = fmax(mx, v[m]); }
    double s = 0;
    #pragma unroll
    for (int m = 0; m < KN; m++) { v[m] = exp(v[m] - mx); s += v[m]; }
    #pragma unroll
    for (int m = 0; m < KN; m++) w[m] = v[m] / s;
  }
  __syncthreads();
  double v[7];
  int cnt = 0;
  double lmin = 1e300, lmax = -1e300;
  for (int k = tid; k < KHW; k += 256) {
    double a = 0;
    #pragma unroll
    for (int m = 0; m < KN; m++) a += cm[((size_t)n * KN + m) * KHW + k] * w[m];
    v[cnt++] = a;
    lmin = fmin(lmin, a);
    lmax = fmax(lmax, a);
  }
  double mn = blockReduceMinD(lmin);
  double mx = blockReduceMaxD(lmax);
  double inv = 1.0 / (mx - mn + 1e-12);
  cnt = 0;
  for (int k = tid; k < KHW; k += 256) {
    double nv = (v[cnt++] - mn) * inv;
    CSAd[(size_t)n * KHW + k] = nv;
    CSAf[(size_t)n * KHW + k] = (float)nv;
  }
}

// rank-based stable descending argsort: idx[rank[i]] = i
__global__ void k_rank(const double* __restrict__ CSAd, int* __restrict__ idx) {
  __shared__ double key[KHW];
  int b = blockIdx.x;
  int n = b / 100, it = b % 100;
  const double* src = CSAd + (size_t)n * KHW;
  for (int j = threadIdx.x; j < KHW; j += 256) key[j] = src[j];
  __syncthreads();
  int wave = threadIdx.x >> 6, lane = threadIdx.x & 63;
  int i0 = it * 16 + wave * 4;
  double ki[4];
  #pragma unroll
  for (int ii = 0; ii < 4; ii++) ki[ii] = key[i0 + ii];
  int r[4] = {0, 0, 0, 0};
  #pragma unroll
  for (int q = 0; q < 25; q++) {
    int j = q * 64 + lane;
    double kj = key[j];
    #pragma unroll
    for (int ii = 0; ii < 4; ii++) {
      int i = i0 + ii;
      r[ii] += (kj > ki[ii]) || (kj == ki[ii] && j < i);
    }
  }
  #pragma unroll
  for (int ii = 0; ii < 4; ii++) {
    int v = r[ii];
    #pragma unroll
    for (int o = 32; o > 0; o >>= 1) v += __shfl_down(v, o);
    if (lane == 0) idx[n * KHW + v] = i0 + ii;
  }
}

// ---------------- stacked weights (n-independent): w1s[(tau,o)][i] ----------------
__global__ void k_prepw1s(const float* __restrict__ w1, const float* __restrict__ wsc,
                          bf16* __restrict__ w1s) {
  int t = blockIdx.x * 256 + threadIdx.x;   // over KM*KHW
  int m = t / KHW, i = t % KHW;
  int tau = m >> 7, o = m & 127;
  float v = (tau < 9) ? w1[((size_t)o * KHW + i) * 9 + tau]
                      : wsc[(size_t)o * KHW + i];
  w1s[t] = __float2bfloat16(v);
}

__global__ void k_prepw2(const float* __restrict__ w2, bf16* __restrict__ w2p) {
  int t = blockIdx.x * 256 + threadIdx.x;
  if (t >= KOC * 9 * KOC) return;
  int o = t / (9 * KOC), r = t % (9 * KOC);
  int s = r / KOC, i = r % KOC;
  w2p[t] = __float2bfloat16(w2[(size_t)o * 9 * KOC + (size_t)i * 9 + s]);
}

// ---------------- zero only the padding borders of Zpad and hpadT ----------------
__global__ void k_zborder(bf16* __restrict__ Zpad, bf16* __restrict__ hpadT) {
  int t = blockIdx.x * 256 + threadIdx.x;
  const int ZW = KN * 164 * (KC / 8);       // 104960
  const int HWm = KN * 164 * (KOC / 8);     // 26240
  int b;
  if (t < ZW) {
    int n = t / (164 * 64), r = t % (164 * 64);
    b = r / 64;
    int c8 = r % 64;
    int y, x;
    if (b < 42) { y = 0; x = b; }
    else if (b < 84) { y = 41; x = b - 42; }
    else if (b < 124) { y = b - 84 + 1; x = 0; }
    else { y = b - 124 + 1; x = 41; }
    short8 z = {};
    *(short8*)((short*)Zpad + ((size_t)n * KPW * KPW + (size_t)y * KPW + x) * KC + c8 * 8) = z;
  } else if (t < ZW + HWm) {
    int u = t - ZW;
    int n = u / (164 * 16), r = u % (164 * 16);
    b = r / 16;
    int c8 = r % 16;
    int y, x;
    if (b < 42) { y = 0; x = b; }
    else if (b < 84) { y = 41; x = b - 42; }
    else if (b < 124) { y = b - 84 + 1; x = 0; }
    else { y = b - 124 + 1; x = 41; }
    short8 z = {};
    *(short8*)((short*)hpadT + ((size_t)n * KPW * KPW + (size_t)y * KPW + x) * KOC + c8 * 8) = z;
  }
}

// ---------------- NF column gather: NFcg[n][c][i] = NFT[n][idx[i]][c] ----------------
__global__ void k_gath2(const short* __restrict__ NFT, const int* __restrict__ idx,
                        short* __restrict__ NFcg) {
  __shared__ short T[32][33];
  int i0 = blockIdx.x * 32, c0 = blockIdx.y * 32, n = blockIdx.z;
  int tx = threadIdx.x, ty = threadIdx.y;
  #pragma unroll
  for (int ii = 0; ii < 4; ii++) {
    int row = ty * 4 + ii;
    int id = idx[n * KHW + i0 + row];
    T[row][tx] = NFT[((size_t)n * KHW + id) * KC + c0 + tx];
  }
  __syncthreads();
  #pragma unroll
  for (int ii = 0; ii < 4; ii++) {
    int cl = ty * 4 + ii;
    NFcg[((size_t)n * KC + c0 + cl) * KHW + i0 + tx] = T[tx][cl];
  }
}

// Zpad[n, y+1, x+1, c] = bf16(NFT[n,p,c] * CSA[n,p])
__global__ void k_zprep(const bf16* __restrict__ NFT, const float* __restrict__ CSAf,
                        bf16* __restrict__ Zpad) {
  int t = blockIdx.x * 256 + threadIdx.x;   // over KN*KHW*KC/4
  const int per_n = KHW * (KC / 4);
  int n = t / per_n, r = t % per_n;
  int p = r / (KC / 4), cq = r % (KC / 4);
  float cs = CSAf[n * KHW + p];
  const short* src = (const short*)(NFT + ((size_t)n * KHW + p) * KC) + cq * 4;
  short4v v = *(const short4v*)src;
  short4v o;
  #pragma unroll
  for (int j = 0; j < 4; j++) {
    short s = v[j];
    bf16 hb = *reinterpret_cast<bf16*>(&s);
    bf16 res = __float2bfloat16(__bfloat162float(hb) * cs);
    o[j] = *reinterpret_cast<short*>(&res);
  }
  int y = p / KH, x = p % KH;
  short* dst = (short*)(Zpad + ((size_t)n * KPW * KPW + (size_t)(y + 1) * KPW + (x + 1)) * KC) + cq * 4;
  *(short4v*)dst = o;
}

// ---------------- GEMM1: U = w1s x NFcg; pipelined BK=64, single-__syncthreads protocol ----
// Per step: issue prefetch(nb) -> ds_read(cb)+MFMA -> __syncthreads (drains prefetch, fence).
// Buffer cb valid from previous step's sync; WAR on cb fenced by sync. Race-free by
// standard __syncthreads semantics (raw s_barrier protocol was runtime-flaky: R7-R9).
__global__ __launch_bounds__(256) void k_gemmU(const short* __restrict__ w1s,
                                               const short* __restrict__ NFcg,
                                               bf16* __restrict__ Uc,
                                               bf16* __restrict__ Usc) {
  __shared__ __align__(16) short smem[24576];  // As[2][4096] | Bs[2][8192] (48 KB); reused as Cs[64][136]
  short* As = smem;
  short* Bs = smem + 8192;
  short* Cs = smem;
  int b = blockIdx.x;
  int workid = (b & 7) * 100 + (b >> 3);       // bijective, 800 % 8 == 0
  int pair = workid / 20;
  int th = workid % 20;
  int n = pair >> 2, c0 = (pair & 3) * 128;
  int tau = th >> 1, half = th & 1;
  int m0 = tau * 128 + half * 64;
  int tid = threadIdx.x, lane = tid & 63, wave = tid >> 6;
  int quad = lane >> 4, l15 = lane & 15;
  int wm = (wave & 1) * 32, wn = (wave >> 1) * 64;
  int sk = ((tid & 7) ^ ((tid >> 3) & 7)) * 8;
  int rowg = tid >> 3;
  const short* Bb = NFcg + (size_t)n * KC * KHW;
  const short* pA[2];
  #pragma unroll
  for (int g = 0; g < 2; g++)
    pA[g] = w1s + (size_t)(m0 + g * 32 + rowg) * KHW + sk;
  const short* pB[4];
  #pragma unroll
  for (int g = 0; g < 4; g++)
    pB[g] = Bb + (size_t)(c0 + g * 32 + rowg) * KHW + sk;
  char* lA = (char*)As + tid * 16;
  char* lB = (char*)Bs + tid * 16;
  int bq = (l15 >> 2) & 1;
  int qx = (quad ^ (l15 & 3)) * 8;
  int koff0 = 32 * bq + qx;
  int koff1 = 32 * (1 - bq) + qx;
  f32x4 acc[2][4] = {};
  gload16(pA[0], lA); gload16(pA[1], lA + 4096);
  gload16(pB[0], lB); gload16(pB[1], lB + 4096);
  gload16(pB[2], lB + 8192); gload16(pB[3], lB + 12288);
  __syncthreads();                             // buf0 landed for all waves
  const int NS = 25;
  for (int s = 0; s < NS; s++) {
    int cb = s & 1, nb = cb ^ 1;
    if (s + 1 < NS) {
      int off = (s + 1) * 64;
      char* la = lA + nb * 8192;
      char* lb = lB + nb * 16384;
      gload16(pA[0] + off, la); gload16(pA[1] + off, la + 4096);
      gload16(pB[0] + off, lb); gload16(pB[1] + off, lb + 4096);
      gload16(pB[2] + off, lb + 8192); gload16(pB[3] + off, lb + 12288);
    }
    const short* Ab = As + cb * 4096;
    const short* Bbf = Bs + cb * 8192;
    #pragma unroll
    for (int ks = 0; ks < 2; ks++) {
      int ko = (ks == 0) ? koff0 : koff1;
      short8 av[2], bv[4];
      #pragma unroll
      for (int t = 0; t < 2; t++) av[t] = *(const short8*)&Ab[(wm + t * 16 + l15) * 64 + ko];
      #pragma unroll
      for (int t = 0; t < 4; t++) bv[t] = *(const short8*)&Bbf[(wn + t * 16 + l15) * 64 + ko];
      #pragma unroll
      for (int ti = 0; ti < 2; ti++)
        #pragma unroll
        for (int tj = 0; tj < 4; tj++)
          acc[ti][tj] = __builtin_amdgcn_mfma_f32_16x16x32_bf16(av[ti], bv[tj], acc[ti][tj], 0, 0, 0);
    }
    __syncthreads();                           // drains prefetch; fences WAR on cb
  }
  #pragma unroll
  for (int ti = 0; ti < 2; ti++) {
    int lr = wm + ti * 16 + quad * 4;
    #pragma unroll
    for (int tj = 0; tj < 4; tj++) {
      int lc = wn + tj * 16 + l15;
      #pragma unroll
      for (int r = 0; r < 4; r++)
        *(bf16*)&Cs[(lr + r) * 136 + lc] = __float2bfloat16(acc[ti][tj][r]);
    }
  }
  __syncthreads();
  int dyq = tau / 3, dxq = tau % 3;
  #pragma unroll
  for (int pass = 0; pass < 4; pass++) {
    int row = pass * 16 + (tid >> 4);
    int col = (tid & 15) * 8;
    if (tau < 9) {
      *(float4*)&Uc[((size_t)((n * 3 + dyq) * 128 + half * 64 + row)) * 1536 + dxq * 512 + c0 + col] =
          *(const float4*)&Cs[row * 136 + col];
    } else {
      *(float4*)&Usc[((size_t)(n * 128 + half * 64 + row)) * 512 + c0 + col] =
          *(const float4*)&Cs[row * 136 + col];
    }
  }
}

// ---------------- convh: dy-split pipelined GEMM, single-__syncthreads protocol ----------
__global__ __launch_bounds__(256) void k_convh(const short* __restrict__ Uc,
                                               const short* __restrict__ Usc,
                                               const short* __restrict__ Zpad,
                                               float* __restrict__ Hpart) {
  __shared__ __align__(16) short smem[24576];  // As[2][8192] | Bs[2][4096]  (48 KB)
  short* As = smem;
  short* Bs = smem + 16384;
  int b = blockIdx.x;
  int wgid = (b & 7) * 125 + (b >> 3);         // bijective, 1000 % 8 == 0
  int n = wgid / 100, rest = wgid % 100;
  int dy = rest / 25, pt = rest % 25;
  int p0 = pt * 64;
  int tid = threadIdx.x, lane = tid & 63, wave = tid >> 6;
  int quad = lane >> 4, l15 = lane & 15;
  int wm = (wave & 1) * 64, wn = (wave >> 1) * 32;
  int sk = ((tid & 7) ^ ((tid >> 3) & 7)) * 8;
  int rowg = tid >> 3;
  bool isconv = (dy < 3);
  const short* Zb = Zpad + (size_t)n * KPW * KPW * KC;
  const short* Abase = isconv ? Uc + ((size_t)((n * 3 + dy) * 128)) * 1536
                              : Usc + ((size_t)(n * 128)) * 512;
  int astr = isconv ? 1536 : 512;
  const short* pA[4];
  #pragma unroll
  for (int g = 0; g < 4; g++)
    pA[g] = Abase + (size_t)(g * 32 + rowg) * astr + sk;
  const short* pB[2];
  #pragma unroll
  for (int g = 0; g < 2; g++) {
    int p = p0 + g * 32 + rowg;
    int y = p / KH, x = p % KH;
    int yy = isconv ? (y + dy) : (y + 1);
    int xx = isconv ? x : (x + 1);
    pB[g] = Zb + ((size_t)yy * KPW + xx) * KC + sk;
  }
  char* lA = (char*)As + tid * 16;
  char* lB = (char*)Bs + tid * 16;
  int NS = isconv ? 24 : 8;
  int bq = (l15 >> 2) & 1;
  int qx = (quad ^ (l15 & 3)) * 8;
  int koff0 = 32 * bq + qx;
  int koff1 = 32 * (1 - bq) + qx;
  f32x4 acc[4][2] = {};
  gload16(pA[0], lA); gload16(pA[1], lA + 4096);
  gload16(pA[2], lA + 8192); gload16(pA[3], lA + 12288);
  gload16(pB[0], lB); gload16(pB[1], lB + 4096);
  __syncthreads();                             // buf0 landed
  for (int s = 0; s < NS; s++) {
    int cb = s & 1, nb = cb ^ 1;
    if (s + 1 < NS) {
      int off = (s + 1) * 64;
      char* la = lA + nb * 16384;
      char* lb = lB + nb * 8192;
      gload16(pA[0] + off, la); gload16(pA[1] + off, la + 4096);
      gload16(pA[2] + off, la + 8192); gload16(pA[3] + off, la + 12288);
      gload16(pB[0] + off, lb); gload16(pB[1] + off, lb + 4096);
    }
    const short* Ab = As + cb * 8192;
    const short* Bb = Bs + cb * 4096;
    #pragma unroll
    for (int ks = 0; ks < 2; ks++) {
      int ko = (ks == 0) ? koff0 : koff1;
      short8 av[4], bv[2];
      #pragma unroll
      for (int t = 0; t < 4; t++) av[t] = *(const short8*)&Ab[(wm + t * 16 + l15) * 64 + ko];
      #pragma unroll
      for (int t = 0; t < 2; t++) bv[t] = *(const short8*)&Bb[(wn + t * 16 + l15) * 64 + ko];
      #pragma unroll
      for (int ti = 0; ti < 4; ti++)
        #pragma unroll
        for (int tj = 0; tj < 2; tj++)
          acc[ti][tj] = __builtin_amdgcn_mfma_f32_16x16x32_bf16(av[ti], bv[tj], acc[ti][tj], 0, 0, 0);
    }
    __syncthreads();                           // drains prefetch; fences WAR on cb
  }
  float* cbp = Hpart + ((size_t)(dy * KN + n)) * KOC * KHW;
  #pragma unroll
  for (int ti = 0; ti < 4; ti++) {
    int o = wm + ti * 16 + quad * 4;
    #pragma unroll
    for (int tj = 0; tj < 2; tj++) {
      int q = p0 + wn + tj * 16 + l15;
      #pragma unroll
      for (int r = 0; r < 4; r++)
        cbp[(size_t)(o + r) * KHW + q] = acc[ti][tj][r];
    }
  }
}

// hpadT[n, y+1, x+1, o] = bf16(relu(b1[o] + Hpart[0]+Hpart[1]+Hpart[2]))
__global__ void k_hprep3(const float* __restrict__ Hpart, const float* __restrict__ b1,
                         bf16* __restrict__ hpadT) {
  __shared__ float T[32][132];
  int n = blockIdx.y, p0 = blockIdx.x * 32;
  int tx = threadIdx.x, ty = threadIdx.y;
  const size_t str = (size_t)KN * KOC * KHW;
  const float* hb = Hpart + (size_t)n * KOC * KHW;
  #pragma unroll
  for (int oc = 0; oc < 16; oc++) {
    int o = oc * 8 + ty;
    size_t off = (size_t)o * KHW + p0 + tx;
    T[tx][o] = fmaxf(hb[off] + hb[str + off] + hb[2 * str + off] + b1[o], 0.0f);
  }
  __syncthreads();
  bf16* hp = hpadT + (size_t)n * KPW * KPW * KOC;
  #pragma unroll
  for (int pc = 0; pc < 4; pc++) {
    int pl = ty * 4 + pc;
    int pp = p0 + pl;
    int yy = pp / KH, xx = pp % KH;
    bf16* row = hp + ((size_t)(yy + 1) * KPW + (xx + 1)) * KOC;
    #pragma unroll
    for (int u = 0; u < 4; u++) row[tx * 4 + u] = __float2bfloat16(T[pl][tx * 4 + u]);
  }
}

// ---------------- conv2 (3x3, 128->128): pipelined, single-__syncthreads protocol ---------
// 750 blocks = 10n * 3dy * 25pt, bijective XCD swizzle (750 = 8*93+6).
__global__ __launch_bounds__(256) void k_conv2(const short* __restrict__ w2p,
                                               const short* __restrict__ hpadT,
                                               float* __restrict__ Cpart) {
  __shared__ __align__(16) short smem[24576];
  short* As = smem;
  short* Bs = smem + 16384;
  int b = blockIdx.x;
  int xcd = b & 7, bi = b >> 3;
  int wgid = (xcd < 6 ? xcd * 94 : 6 * 94 + (xcd - 6) * 93) + bi;
  int n = wgid / 75, rest = wgid % 75;
  int dy = rest / 25, pt = rest % 25;
  int p0 = pt * 64;
  int tid = threadIdx.x, lane = tid & 63, wave = tid >> 6;
  int quad = lane >> 4, l15 = lane & 15;
  int wm = (wave & 1) * 64, wn = (wave >> 1) * 32;
  int sk = ((tid & 7) ^ ((tid >> 3) & 7)) * 8;
  int rowg = tid >> 3;
  const short* hb = hpadT + (size_t)n * KPW * KPW * KOC;
  const short* pA[4];
  #pragma unroll
  for (int g = 0; g < 4; g++)
    pA[g] = w2p + (size_t)(g * 32 + rowg) * (9 * KOC) + dy * 384 + sk;
  const short* pB[2];
  #pragma unroll
  for (int g = 0; g < 2; g++) {
    int p = p0 + g * 32 + rowg;
    int y = p / KH, x = p % KH;
    pB[g] = hb + ((size_t)(y + dy) * KPW + x) * KOC + sk;   // k = dx*128+c contiguous
  }
  char* lA = (char*)As + tid * 16;
  char* lB = (char*)Bs + tid * 16;
  const int NS = 6;                            // K = 384 = 6 * 64
  int bq = (l15 >> 2) & 1;
  int qx = (quad ^ (l15 & 3)) * 8;
  int koff0 = 32 * bq + qx;
  int koff1 = 32 * (1 - bq) + qx;
  f32x4 acc[4][2] = {};
  gload16(pA[0], lA); gload16(pA[1], lA + 4096);
  gload16(pA[2], lA + 8192); gload16(pA[3], lA + 12288);
  gload16(pB[0], lB); gload16(pB[1], lB + 4096);
  __syncthreads();                             // buf0 landed
  for (int s = 0; s < NS; s++) {
    int cb = s & 1, nb = cb ^ 1;
    if (s + 1 < NS) {
      int off = (s + 1) * 64;
      char* la = lA + nb * 16384;
      char* lb = lB + nb * 8192;
      gload16(pA[0] + off, la); gload16(pA[1] + off, la + 4096);
      gload16(pA[2] + off, la + 8192); gload16(pA[3] + off, la + 12288);
      gload16(pB[0] + off, lb); gload16(pB[1] + off, lb + 4096);
    }
    const short* Ab = As + cb * 8192;
    const short* Bb = Bs + cb * 4096;
    #pragma unroll
    for (int ks = 0; ks < 2; ks++) {
      int ko = (ks == 0) ? koff0 : koff1;
      short8 av[4], bv[2];
      #pragma unroll
      for (int t = 0; t < 4; t++) av[t] = *(const short8*)&Ab[(wm + t * 16 + l15) * 64 + ko];
      #pragma unroll
      for (int t = 0; t < 2; t++) bv[t] = *(const short8*)&Bb[(wn + t * 16 + l15) * 64 + ko];
      #pragma unroll
      for (int ti = 0; ti < 4; ti++)
        #pragma unroll
        for (int tj = 0; tj < 2; tj++)
          acc[ti][tj] = __builtin_amdgcn_mfma_f32_16x16x32_bf16(av[ti], bv[tj], acc[ti][tj], 0, 0, 0);
    }
    __syncthreads();                           // drains prefetch; fences WAR on cb
  }
  float* cbp = Cpart + ((size_t)(dy * KN + n)) * KOC * KHW;
  #pragma unroll
  for (int ti = 0; ti < 4; ti++) {
    int o = wm + ti * 16 + quad * 4;
    #pragma unroll
    for (int tj = 0; tj < 2; tj++) {
      int q = p0 + wn + tj * 16 + l15;
      #pragma unroll
      for (int r = 0; r < 4; r++)
        cbp[(size_t)(o + r) * KHW + q] = acc[ti][tj][r];
    }
  }
}

// out = relu(sum_dy Cpart + b2 + shortcut(Hpart[3]) + bs)
__global__ void k_final2(const float* __restrict__ Cpart, const float* __restrict__ Hpart,
                         const float* __restrict__ b2, const float* __restrict__ bs,
                         float* __restrict__ out) {
  int t = blockIdx.x * 256 + threadIdx.x;
  if (t >= KN * KOC * KHW) return;
  int o = (t / KHW) % KOC;
  const size_t stride = (size_t)KN * KOC * KHW;
  float v = Cpart[t] + Cpart[stride + t] + Cpart[2 * stride + t] +
            Hpart[3 * stride + t] + b2[o] + bs[o];
  out[t] = fmaxf(v, 0.0f);
}

// ---------------- launch ----------------
extern "C" void kernel_launch(void* const* d_in, const int* in_sizes, int n_in,
                              void* d_out, int out_size, void* d_ws, size_t ws_size,
                              hipStream_t stream) {
  const float* feats = (const float*)d_in[0];
  const float* sisms = (const float*)d_in[1];
  const float* w1 = (const float*)d_in[2];
  const float* b1 = (const float*)d_in[3];
  const float* w2 = (const float*)d_in[4];
  const float* b2 = (const float*)d_in[5];
  const float* wsc = (const float*)d_in[6];
  const float* bsc = (const float*)d_in[7];
  float* out = (float*)d_out;

  char* w = (char*)d_ws;
  auto carve = [&](size_t bytes) -> void* {
    void* p = (void*)w;
    w += (bytes + 255) & ~(size_t)255;
    return p;
  };
  bf16* NFT   = (bf16*)carve((size_t)KN * KHW * KC * 2);          // 16.4 MB
  bf16* NFcg  = (bf16*)carve((size_t)KN * KC * KHW * 2);          // 16.4 MB
  bf16* Uc    = (bf16*)carve((size_t)KN * 3 * 128 * 1536 * 2);    // 11.8 MB
  bf16* Usc   = (bf16*)carve((size_t)KN * 128 * 512 * 2);         // 1.3 MB
  bf16* w1s   = (bf16*)carve((size_t)KM * KHW * 2);               // 4.1 MB
  bf16* Zpad  = (bf16*)carve((size_t)KN * KPW * KPW * KC * 2);    // 18.1 MB
  bf16* hpadT = (bf16*)carve((size_t)KN * KPW * KPW * KOC * 2);   // 4.5 MB
  float* Hpart = (float*)carve((size_t)4 * KN * KOC * KHW * 4);   // 32.8 MB
  float* Cpart = (float*)carve((size_t)3 * KN * KOC * KHW * 4);   // 24.6 MB
  bf16* w2p   = (bf16*)carve((size_t)KOC * 9 * KOC * 2);
  double* psbuf = (double*)carve((size_t)16 * KN * KHW * 8);      // 2.05 MB
  double* rnorm = (double*)carve((size_t)KN * KHW * 8);
  double* vpp   = (double*)carve((size_t)KN * KC * 50 * 8);       // 2.05 MB
  double* SIV   = (double*)carve((size_t)KN * KC * 8);
  double* cmp   = (double*)carve((size_t)16 * KN * KN * KHW * 8); // 20.5 MB
  double* cm    = (double*)carve((size_t)KN * KN * KHW * 8);
  double* tbuf  = (double*)carve((size_t)KN * KN * 8);
  double* CSAd  = (double*)carve((size_t)KN * KHW * 8);
  float* CSAf   = (float*)carve((size_t)KN * KHW * 4);
  int* idxb     = (int*)carve((size_t)KN * KHW * 4);

  k_zborder<<<513, 256, 0, stream>>>(Zpad, hpadT);

  k_rnormp<<<dim3(63, 16), 256, 0, stream>>>(feats, psbuf);
  k_rnormc<<<63, 256, 0, stream>>>(psbuf, rnorm);
  k_nft<<<dim3(50, 16, KN), dim3(32, 8), 0, stream>>>(feats, rnorm, sisms, NFT, vpp);
  k_sivnorm2<<<KN, 512, 0, stream>>>(vpp, SIV);
  k_cmP<<<dim3(7, 16, KN), 256, 0, stream>>>(feats, SIV, cmp);
  k_cmBN<<<KN * KN, 512, 0, stream>>>(cmp, rnorm, cm);
  k_st<<<KN * KN, 256, 0, stream>>>(cm, tbuf);
  k_csa<<<KN, 256, 0, stream>>>(cm, tbuf, CSAd, CSAf);
  k_rank<<<1000, 256, 0, stream>>>(CSAd, idxb);

  k_prepw1s<<<KM * KHW / 256, 256, 0, stream>>>(w1, wsc, w1s);
  k_prepw2<<<576, 256, 0, stream>>>(w2, w2p);
  k_gath2<<<dim3(50, 16, KN), dim3(32, 8), 0, stream>>>((const short*)NFT, idxb, (short*)NFcg);
  k_zprep<<<KN * KHW * (KC / 4) / 256, 256, 0, stream>>>(NFT, CSAf, Zpad);

  k_gemmU<<<800, 256, 0, stream>>>((const short*)w1s, (const short*)NFcg, Uc, Usc);
  k_convh<<<1000, 256, 0, stream>>>((const short*)Uc, (const short*)Usc,
                                    (const short*)Zpad, Hpart);
  k_hprep3<<<dim3(50, KN), dim3(32, 8), 0, stream>>>(Hpart, b1, hpadT);
  k_conv2<<<750, 256, 0, stream>>>((const short*)w2p, (const short*)hpadT, Cpart);
  k_final2<<<8000, 256, 0, stream>>>(Cpart, Hpart, b2, bsc, out);
}

// Round 12
// 270.629 us; speedup vs baseline: 1.0163x; 1.0163x over previous
//
#include <hip/hip_runtime.h>
#include <hip/hip_bf16.h>
#include <math.h>

typedef short short8 __attribute__((ext_vector_type(8)));
typedef short short4v __attribute__((ext_vector_type(4)));
typedef float f32x4 __attribute__((ext_vector_type(4)));
typedef __hip_bfloat16 bf16;

// problem constants
#define KN 10
#define KC 512
#define KHW 1600
#define KH 40
#define KOC 128
#define KPW 42   // padded spatial (40+2)
#define KM 1280  // stacked M: 9 conv taps * 128 + 128 shortcut

// direct global->LDS DMA, 16B per lane. LDS dest must be wave-uniform base + lane*16.
__device__ __forceinline__ void gload16(const void* g, void* l) {
  __builtin_amdgcn_global_load_lds(
      (const __attribute__((address_space(1))) unsigned int*)g,
      (__attribute__((address_space(3))) unsigned int*)l, 16, 0, 0);
}

// ---------------- block reduction helpers (fp64) ----------------
__device__ __forceinline__ double blockReduceSumD(double v) {
  __shared__ double tmpS[8];
  int lane = threadIdx.x & 63, wv = threadIdx.x >> 6;
  #pragma unroll
  for (int o = 32; o > 0; o >>= 1) v += __shfl_down(v, o);
  if (lane == 0) tmpS[wv] = v;
  __syncthreads();
  if (threadIdx.x == 0) {
    int nw = (blockDim.x + 63) >> 6;
    double s = 0;
    for (int i = 0; i < nw; i++) s += tmpS[i];
    tmpS[0] = s;
  }
  __syncthreads();
  double r = tmpS[0];
  __syncthreads();
  return r;
}

__device__ __forceinline__ double blockReduceMinD(double v) {
  __shared__ double tmpMn[8];
  int lane = threadIdx.x & 63, wv = threadIdx.x >> 6;
  #pragma unroll
  for (int o = 32; o > 0; o >>= 1) v = fmin(v, __shfl_down(v, o));
  if (lane == 0) tmpMn[wv] = v;
  __syncthreads();
  if (threadIdx.x == 0) {
    int nw = (blockDim.x + 63) >> 6;
    double s = tmpMn[0];
    for (int i = 1; i < nw; i++) s = fmin(s, tmpMn[i]);
    tmpMn[0] = s;
  }
  __syncthreads();
  double r = tmpMn[0];
  __syncthreads();
  return r;
}

__device__ __forceinline__ double blockReduceMaxD(double v) {
  __shared__ double tmpMx[8];
  int lane = threadIdx.x & 63, wv = threadIdx.x >> 6;
  #pragma unroll
  for (int o = 32; o > 0; o >>= 1) v = fmax(v, __shfl_down(v, o));
  if (lane == 0) tmpMx[wv] = v;
  __syncthreads();
  if (threadIdx.x == 0) {
    int nw = (blockDim.x + 63) >> 6;
    double s = tmpMx[0];
    for (int i = 1; i < nw; i++) s = fmax(s, tmpMx[i]);
    tmpMx[0] = s;
  }
  __syncthreads();
  double r = tmpMx[0];
  __syncthreads();
  return r;
}

// ---------------- small chain (fp64 for argsort stability) ----------------

// 16 channel-slices of 32: 1008 blocks
__global__ void k_rnormp(const float* __restrict__ feats, double* __restrict__ ps) {
  int t = blockIdx.x * 256 + threadIdx.x;
  if (t >= KN * KHW) return;
  int ci = blockIdx.y;
  int n = t / KHW, k = t % KHW;
  const float* p = feats + (size_t)n * KC * KHW + (size_t)ci * 32 * KHW + k;
  double s = 0.0;
  #pragma unroll
  for (int c = 0; c < 32; ++c) { double v = p[(size_t)c * KHW]; s += v * v; }
  ps[(size_t)ci * KN * KHW + t] = s;
}

__global__ void k_rnormc(const double* __restrict__ ps, double* __restrict__ rnorm) {
  int t = blockIdx.x * 256 + threadIdx.x;
  if (t >= KN * KHW) return;
  double s = 0;
  #pragma unroll
  for (int ci = 0; ci < 16; ci++) s += ps[(size_t)ci * KN * KHW + t];
  double nn = sqrt(s);
  if (nn < 1e-12) nn = 1e-12;
  rnorm[t] = 1.0 / nn;
}

// NFT[n,k,c] = bf16(feats[n,c,k] * rnorm[n,k]); also emits SIV pre-partials
__global__ void k_nft(const float* __restrict__ feats, const double* __restrict__ rnorm,
                      const float* __restrict__ sism, bf16* __restrict__ NFT,
                      double* __restrict__ vpp) {
  __shared__ float T[32][33];
  int n = blockIdx.z, k0 = blockIdx.x * 32, c0 = blockIdx.y * 32;
  int tx = threadIdx.x, ty = threadIdx.y;
  const float* fb = feats + ((size_t)n * KC + c0) * KHW + k0;
  #pragma unroll
  for (int ii = 0; ii < 4; ii++) {
    int cl = ty * 4 + ii;
    T[cl][tx] = fb[(size_t)cl * KHW + tx];
  }
  __syncthreads();
  bf16* ob = NFT + ((size_t)n * KHW + k0) * KC + c0;
  #pragma unroll
  for (int ii = 0; ii < 4; ii++) {
    int kl = ty * 4 + ii;
    float r = (float)rnorm[n * KHW + k0 + kl];
    ob[(size_t)kl * KC + tx] = __float2bfloat16(T[tx][kl] * r);
  }
  double rs = rnorm[n * KHW + k0 + tx] * (double)sism[n * KHW + k0 + tx];
  #pragma unroll
  for (int ii = 0; ii < 4; ii++) {
    int cl = ty * 4 + ii;
    double v = (double)T[cl][tx] * rs;
    #pragma unroll
    for (int o = 16; o > 0; o >>= 1) v += __shfl_down(v, o, 32);
    if (tx == 0) vpp[((size_t)n * KC + c0 + cl) * 50 + k0 / 32] = v;
  }
}

__global__ void k_sivnorm2(const double* __restrict__ vpp, double* __restrict__ SIV) {
  int n = blockIdx.x, c = threadIdx.x;   // 512 threads
  const double* p = vpp + ((size_t)n * KC + c) * 50;
  double acc = 0;
  #pragma unroll 5
  for (int j = 0; j < 50; j++) acc += p[j];
  acc /= (double)KHW;
  double s2 = blockReduceSumD(acc * acc);
  double nn = sqrt(s2);
  if (nn < 1e-12) nn = 1e-12;
  SIV[n * KC + c] = acc / nn;
}

// 16 channel-slices of 32: 1120 blocks
__global__ void k_cmP(const float* __restrict__ feats, const double* __restrict__ SIV,
                      double* __restrict__ cmp) {
  __shared__ double sv[KN][32];
  int kc = blockIdx.x, ci = blockIdx.y, n = blockIdx.z;
  for (int t = threadIdx.x; t < KN * 32; t += 256) {
    int m = t / 32, c = t % 32;
    sv[m][c] = SIV[m * KC + ci * 32 + c];
  }
  __syncthreads();
  int k = kc * 256 + threadIdx.x;
  if (k >= KHW) return;
  const float* f = feats + ((size_t)n * KC + ci * 32) * KHW + k;
  double acc[KN];
  #pragma unroll
  for (int m = 0; m < KN; m++) acc[m] = 0.0;
  for (int c = 0; c < 32; ++c) {
    double fv = f[(size_t)c * KHW];
    #pragma unroll
    for (int m = 0; m < KN; m++) acc[m] += fv * sv[m][c];
  }
  const size_t str = (size_t)KN * KN * KHW;
  #pragma unroll
  for (int m = 0; m < KN; m++)
    cmp[(size_t)ci * str + ((size_t)n * KN + m) * KHW + k] = acc[m];
}

// fused cmB + cmnorm
__global__ void k_cmBN(const double* __restrict__ cmp, const double* __restrict__ rnorm,
                       double* __restrict__ cm) {
  int b = blockIdx.x;                       // 100 = n*KN + m
  int n = b / KN;
  const size_t str = (size_t)KN * KN * KHW;
  const size_t rb = (size_t)b * KHW;
  double v[4];
  int cnt = 0;
  double ss = 0;
  for (int k = threadIdx.x; k < KHW; k += 512) {
    double s = 0;
    #pragma unroll
    for (int ci = 0; ci < 16; ci++) s += cmp[ci * str + rb + k];
    s *= rnorm[n * KHW + k];
    v[cnt++] = s;
    ss += s * s;
  }
  ss = blockReduceSumD(ss);
  double nn = sqrt(ss);
  if (nn < 1e-12) nn = 1e-12;
  double rn = 1.0 / nn;
  cnt = 0;
  for (int k = threadIdx.x; k < KHW; k += 512) cm[rb + k] = v[cnt++] * rn;
}

__global__ void k_st(const double* __restrict__ cm, double* __restrict__ tbuf) {
  int b = blockIdx.x;
  int n = b / KN, m = b % KN;
  const double* base = cm + (size_t)n * KN * KHW;
  double acc = 0;
  for (int k = threadIdx.x; k < KHW; k += 256) {
    double S = 0;
    #pragma unroll
    for (int mm = 0; mm < KN; mm++) S += base[(size_t)mm * KHW + k];
    acc += base[(size_t)m * KHW + k] * S;
  }
  acc = blockReduceSumD(acc);
  if (threadIdx.x == 0) tbuf[b] = acc;
}

__global__ void k_csa(const double* __restrict__ cm, const double* __restrict__ tbuf,
                      double* __restrict__ CSAd, float* __restrict__ CSAf) {
  __shared__ double w[KN];
  int n = blockIdx.x, tid = threadIdx.x;
  if (tid == 0) {
    double v[KN], mx = -1e300;
    #pragma unroll
    for (int m = 0; m < KN; m++) { v[m] = tbuf[n * KN + m]; mx = fmax(mx, v[m]); }
    double s = 0;
    #pragma unroll
    for (int m = 0; m < KN; m++) { v[m] = exp(v[m] - mx); s += v[m]; }
    #pragma unroll
    for (int m = 0; m < KN; m++) w[m] = v[m] / s;
  }
  __syncthreads();
  double v[7];
  int cnt = 0;
  double lmin = 1e300, lmax = -1e300;
  for (int k = tid; k < KHW; k += 256) {
    double a = 0;
    #pragma unroll
    for (int m = 0; m < KN; m++) a += cm[((size_t)n * KN + m) * KHW + k] * w[m];
    v[cnt++] = a;
    lmin = fmin(lmin, a);
    lmax = fmax(lmax, a);
  }
  double mn = blockReduceMinD(lmin);
  double mx = blockReduceMaxD(lmax);
  double inv = 1.0 / (mx - mn + 1e-12);
  cnt = 0;
  for (int k = tid; k < KHW; k += 256) {
    double nv = (v[cnt++] - mn) * inv;
    CSAd[(size_t)n * KHW + k] = nv;
    CSAf[(size_t)n * KHW + k] = (float)nv;
  }
}

// rank-based stable descending argsort: idx[rank[i]] = i
__global__ void k_rank(const double* __restrict__ CSAd, int* __restrict__ idx) {
  __shared__ double key[KHW];
  int b = blockIdx.x;
  int n = b / 100, it = b % 100;
  const double* src = CSAd + (size_t)n * KHW;
  for (int j = threadIdx.x; j < KHW; j += 256) key[j] = src[j];
  __syncthreads();
  int wave = threadIdx.x >> 6, lane = threadIdx.x & 63;
  int i0 = it * 16 + wave * 4;
  double ki[4];
  #pragma unroll
  for (int ii = 0; ii < 4; ii++) ki[ii] = key[i0 + ii];
  int r[4] = {0, 0, 0, 0};
  #pragma unroll
  for (int q = 0; q < 25; q++) {
    int j = q * 64 + lane;
    double kj = key[j];
    #pragma unroll
    for (int ii = 0; ii < 4; ii++) {
      int i = i0 + ii;
      r[ii] += (kj > ki[ii]) || (kj == ki[ii] && j < i);
    }
  }
  #pragma unroll
  for (int ii = 0; ii < 4; ii++) {
    int v = r[ii];
    #pragma unroll
    for (int o = 32; o > 0; o >>= 1) v += __shfl_down(v, o);
    if (lane == 0) idx[n * KHW + v] = i0 + ii;
  }
}

// ---------------- stacked weights (n-independent): w1s[(tau,o)][i] ----------------
__global__ void k_prepw1s(const float* __restrict__ w1, const float* __restrict__ wsc,
                          bf16* __restrict__ w1s) {
  int t = blockIdx.x * 256 + threadIdx.x;   // over KM*KHW
  int m = t / KHW, i = t % KHW;
  int tau = m >> 7, o = m & 127;
  float v = (tau < 9) ? w1[((size_t)o * KHW + i) * 9 + tau]
                      : wsc[(size_t)o * KHW + i];
  w1s[t] = __float2bfloat16(v);
}

__global__ void k_prepw2(const float* __restrict__ w2, bf16* __restrict__ w2p) {
  int t = blockIdx.x * 256 + threadIdx.x;
  if (t >= KOC * 9 * KOC) return;
  int o = t / (9 * KOC), r = t % (9 * KOC);
  int s = r / KOC, i = r % KOC;
  w2p[t] = __float2bfloat16(w2[(size_t)o * 9 * KOC + (size_t)i * 9 + s]);
}

// ---------------- zero only the padding borders of Zpad and hpadT ----------------
__global__ void k_zborder(bf16* __restrict__ Zpad, bf16* __restrict__ hpadT) {
  int t = blockIdx.x * 256 + threadIdx.x;
  const int ZW = KN * 164 * (KC / 8);       // 104960
  const int HWm = KN * 164 * (KOC / 8);     // 26240
  int b;
  if (t < ZW) {
    int n = t / (164 * 64), r = t % (164 * 64);
    b = r / 64;
    int c8 = r % 64;
    int y, x;
    if (b < 42) { y = 0; x = b; }
    else if (b < 84) { y = 41; x = b - 42; }
    else if (b < 124) { y = b - 84 + 1; x = 0; }
    else { y = b - 124 + 1; x = 41; }
    short8 z = {};
    *(short8*)((short*)Zpad + ((size_t)n * KPW * KPW + (size_t)y * KPW + x) * KC + c8 * 8) = z;
  } else if (t < ZW + HWm) {
    int u = t - ZW;
    int n = u / (164 * 16), r = u % (164 * 16);
    b = r / 16;
    int c8 = r % 16;
    int y, x;
    if (b < 42) { y = 0; x = b; }
    else if (b < 84) { y = 41; x = b - 42; }
    else if (b < 124) { y = b - 84 + 1; x = 0; }
    else { y = b - 124 + 1; x = 41; }
    short8 z = {};
    *(short8*)((short*)hpadT + ((size_t)n * KPW * KPW + (size_t)y * KPW + x) * KOC + c8 * 8) = z;
  }
}

// ---------------- NF column gather: NFcg[n][c][i] = NFT[n][idx[i]][c] ----------------
__global__ void k_gath2(const short* __restrict__ NFT, const int* __restrict__ idx,
                        short* __restrict__ NFcg) {
  __shared__ short T[32][33];
  int i0 = blockIdx.x * 32, c0 = blockIdx.y * 32, n = blockIdx.z;
  int tx = threadIdx.x, ty = threadIdx.y;
  #pragma unroll
  for (int ii = 0; ii < 4; ii++) {
    int row = ty * 4 + ii;
    int id = idx[n * KHW + i0 + row];
    T[row][tx] = NFT[((size_t)n * KHW + id) * KC + c0 + tx];
  }
  __syncthreads();
  #pragma unroll
  for (int ii = 0; ii < 4; ii++) {
    int cl = ty * 4 + ii;
    NFcg[((size_t)n * KC + c0 + cl) * KHW + i0 + tx] = T[tx][cl];
  }
}

// Zpad[n, y+1, x+1, c] = bf16(NFT[n,p,c] * CSA[n,p])
__global__ void k_zprep(const bf16* __restrict__ NFT, const float* __restrict__ CSAf,
                        bf16* __restrict__ Zpad) {
  int t = blockIdx.x * 256 + threadIdx.x;   // over KN*KHW*KC/4
  const int per_n = KHW * (KC / 4);
  int n = t / per_n, r = t % per_n;
  int p = r / (KC / 4), cq = r % (KC / 4);
  float cs = CSAf[n * KHW + p];
  const short* src = (const short*)(NFT + ((size_t)n * KHW + p) * KC) + cq * 4;
  short4v v = *(const short4v*)src;
  short4v o;
  #pragma unroll
  for (int j = 0; j < 4; j++) {
    short s = v[j];
    bf16 hb = *reinterpret_cast<bf16*>(&s);
    bf16 res = __float2bfloat16(__bfloat162float(hb) * cs);
    o[j] = *reinterpret_cast<short*>(&res);
  }
  int y = p / KH, x = p % KH;
  short* dst = (short*)(Zpad + ((size_t)n * KPW * KPW + (size_t)(y + 1) * KPW + (x + 1)) * KC) + cq * 4;
  *(short4v*)dst = o;
}

// ---------------- GEMM1: U = w1s x NFcg; pipelined BK=64, single-__syncthreads protocol ----
__global__ __launch_bounds__(256) void k_gemmU(const short* __restrict__ w1s,
                                               const short* __restrict__ NFcg,
                                               bf16* __restrict__ Uc,
                                               bf16* __restrict__ Usc) {
  __shared__ __align__(16) short smem[24576];  // As[2][4096] | Bs[2][8192] (48 KB); reused as Cs[64][136]
  short* As = smem;
  short* Bs = smem + 8192;
  short* Cs = smem;
  int b = blockIdx.x;
  int workid = (b & 7) * 100 + (b >> 3);       // bijective, 800 % 8 == 0
  int pair = workid / 20;
  int th = workid % 20;
  int n = pair >> 2, c0 = (pair & 3) * 128;
  int tau = th >> 1, half = th & 1;
  int m0 = tau * 128 + half * 64;
  int tid = threadIdx.x, lane = tid & 63, wave = tid >> 6;
  int quad = lane >> 4, l15 = lane & 15;
  int wm = (wave & 1) * 32, wn = (wave >> 1) * 64;
  int sk = ((tid & 7) ^ ((tid >> 3) & 7)) * 8;
  int rowg = tid >> 3;
  const short* Bb = NFcg + (size_t)n * KC * KHW;
  const short* pA[2];
  #pragma unroll
  for (int g = 0; g < 2; g++)
    pA[g] = w1s + (size_t)(m0 + g * 32 + rowg) * KHW + sk;
  const short* pB[4];
  #pragma unroll
  for (int g = 0; g < 4; g++)
    pB[g] = Bb + (size_t)(c0 + g * 32 + rowg) * KHW + sk;
  char* lA = (char*)As + tid * 16;
  char* lB = (char*)Bs + tid * 16;
  int bq = (l15 >> 2) & 1;
  int qx = (quad ^ (l15 & 3)) * 8;
  int koff0 = 32 * bq + qx;
  int koff1 = 32 * (1 - bq) + qx;
  f32x4 acc[2][4] = {};
  gload16(pA[0], lA); gload16(pA[1], lA + 4096);
  gload16(pB[0], lB); gload16(pB[1], lB + 4096);
  gload16(pB[2], lB + 8192); gload16(pB[3], lB + 12288);
  __syncthreads();                             // buf0 landed for all waves
  const int NS = 25;
  for (int s = 0; s < NS; s++) {
    int cb = s & 1, nb = cb ^ 1;
    if (s + 1 < NS) {
      int off = (s + 1) * 64;
      char* la = lA + nb * 8192;
      char* lb = lB + nb * 16384;
      gload16(pA[0] + off, la); gload16(pA[1] + off, la + 4096);
      gload16(pB[0] + off, lb); gload16(pB[1] + off, lb + 4096);
      gload16(pB[2] + off, lb + 8192); gload16(pB[3] + off, lb + 12288);
    }
    const short* Ab = As + cb * 4096;
    const short* Bbf = Bs + cb * 8192;
    #pragma unroll
    for (int ks = 0; ks < 2; ks++) {
      int ko = (ks == 0) ? koff0 : koff1;
      short8 av[2], bv[4];
      #pragma unroll
      for (int t = 0; t < 2; t++) av[t] = *(const short8*)&Ab[(wm + t * 16 + l15) * 64 + ko];
      #pragma unroll
      for (int t = 0; t < 4; t++) bv[t] = *(const short8*)&Bbf[(wn + t * 16 + l15) * 64 + ko];
      #pragma unroll
      for (int ti = 0; ti < 2; ti++)
        #pragma unroll
        for (int tj = 0; tj < 4; tj++)
          acc[ti][tj] = __builtin_amdgcn_mfma_f32_16x16x32_bf16(av[ti], bv[tj], acc[ti][tj], 0, 0, 0);
    }
    __syncthreads();                           // drains prefetch; fences WAR on cb
  }
  #pragma unroll
  for (int ti = 0; ti < 2; ti++) {
    int lr = wm + ti * 16 + quad * 4;
    #pragma unroll
    for (int tj = 0; tj < 4; tj++) {
      int lc = wn + tj * 16 + l15;
      #pragma unroll
      for (int r = 0; r < 4; r++)
        *(bf16*)&Cs[(lr + r) * 136 + lc] = __float2bfloat16(acc[ti][tj][r]);
    }
  }
  __syncthreads();
  int dyq = tau / 3, dxq = tau % 3;
  #pragma unroll
  for (int pass = 0; pass < 4; pass++) {
    int row = pass * 16 + (tid >> 4);
    int col = (tid & 15) * 8;
    if (tau < 9) {
      *(float4*)&Uc[((size_t)((n * 3 + dyq) * 128 + half * 64 + row)) * 1536 + dxq * 512 + c0 + col] =
          *(const float4*)&Cs[row * 136 + col];
    } else {
      *(float4*)&Usc[((size_t)(n * 128 + half * 64 + row)) * 512 + c0 + col] =
          *(const float4*)&Cs[row * 136 + col];
    }
  }
}

// ---------------- convh: dy-split pipelined GEMM, single-__syncthreads protocol ----------
// 1000 blocks: conv (long, NS=24) at blockIdx 0..749 (bijective m204 swizzle over 750),
// shortcut (short, NS=8) at 750..999 so the straggler round consists of SHORT blocks.
__global__ __launch_bounds__(256) void k_convh(const short* __restrict__ Uc,
                                               const short* __restrict__ Usc,
                                               const short* __restrict__ Zpad,
                                               float* __restrict__ Hpart) {
  __shared__ __align__(16) short smem[24576];  // As[2][8192] | Bs[2][4096]  (48 KB)
  short* As = smem;
  short* Bs = smem + 16384;
  int b = blockIdx.x;
  bool isconv = (b < 750);
  int n, dy, pt;
  if (isconv) {
    int xcd = b & 7, bi = b >> 3;
    int wgid = (xcd < 6 ? xcd * 94 : 6 * 94 + (xcd - 6) * 93) + bi;   // bijective over 750
    n = wgid / 75;
    int rest = wgid % 75;
    dy = rest / 25; pt = rest % 25;
  } else {
    int u = b - 750;
    n = u / 25; pt = u % 25; dy = 3;
  }
  int p0 = pt * 64;
  int tid = threadIdx.x, lane = tid & 63, wave = tid >> 6;
  int quad = lane >> 4, l15 = lane & 15;
  int wm = (wave & 1) * 64, wn = (wave >> 1) * 32;
  int sk = ((tid & 7) ^ ((tid >> 3) & 7)) * 8;
  int rowg = tid >> 3;
  const short* Zb = Zpad + (size_t)n * KPW * KPW * KC;
  const short* Abase = isconv ? Uc + ((size_t)((n * 3 + dy) * 128)) * 1536
                              : Usc + ((size_t)(n * 128)) * 512;
  int astr = isconv ? 1536 : 512;
  const short* pA[4];
  #pragma unroll
  for (int g = 0; g < 4; g++)
    pA[g] = Abase + (size_t)(g * 32 + rowg) * astr + sk;
  const short* pB[2];
  #pragma unroll
  for (int g = 0; g < 2; g++) {
    int p = p0 + g * 32 + rowg;
    int y = p / KH, x = p % KH;
    int yy = isconv ? (y + dy) : (y + 1);
    int xx = isconv ? x : (x + 1);
    pB[g] = Zb + ((size_t)yy * KPW + xx) * KC + sk;
  }
  char* lA = (char*)As + tid * 16;
  char* lB = (char*)Bs + tid * 16;
  int NS = isconv ? 24 : 8;
  int bq = (l15 >> 2) & 1;
  int qx = (quad ^ (l15 & 3)) * 8;
  int koff0 = 32 * bq + qx;
  int koff1 = 32 * (1 - bq) + qx;
  f32x4 acc[4][2] = {};
  gload16(pA[0], lA); gload16(pA[1], lA + 4096);
  gload16(pA[2], lA + 8192); gload16(pA[3], lA + 12288);
  gload16(pB[0], lB); gload16(pB[1], lB + 4096);
  __syncthreads();                             // buf0 landed
  for (int s = 0; s < NS; s++) {
    int cb = s & 1, nb = cb ^ 1;
    if (s + 1 < NS) {
      int off = (s + 1) * 64;
      char* la = lA + nb * 16384;
      char* lb = lB + nb * 8192;
      gload16(pA[0] + off, la); gload16(pA[1] + off, la + 4096);
      gload16(pA[2] + off, la + 8192); gload16(pA[3] + off, la + 12288);
      gload16(pB[0] + off, lb); gload16(pB[1] + off, lb + 4096);
    }
    const short* Ab = As + cb * 8192;
    const short* Bb = Bs + cb * 4096;
    #pragma unroll
    for (int ks = 0; ks < 2; ks++) {
      int ko = (ks == 0) ? koff0 : koff1;
      short8 av[4], bv[2];
      #pragma unroll
      for (int t = 0; t < 4; t++) av[t] = *(const short8*)&Ab[(wm + t * 16 + l15) * 64 + ko];
      #pragma unroll
      for (int t = 0; t < 2; t++) bv[t] = *(const short8*)&Bb[(wn + t * 16 + l15) * 64 + ko];
      #pragma unroll
      for (int ti = 0; ti < 4; ti++)
        #pragma unroll
        for (int tj = 0; tj < 2; tj++)
          acc[ti][tj] = __builtin_amdgcn_mfma_f32_16x16x32_bf16(av[ti], bv[tj], acc[ti][tj], 0, 0, 0);
    }
    __syncthreads();                           // drains prefetch; fences WAR on cb
  }
  float* cbp = Hpart + ((size_t)(dy * KN + n)) * KOC * KHW;
  #pragma unroll
  for (int ti = 0; ti < 4; ti++) {
    int o = wm + ti * 16 + quad * 4;
    #pragma unroll
    for (int tj = 0; tj < 2; tj++) {
      int q = p0 + wn + tj * 16 + l15;
      #pragma unroll
      for (int r = 0; r < 4; r++)
        cbp[(size_t)(o + r) * KHW + q] = acc[ti][tj][r];
    }
  }
}

// hpadT[n, y+1, x+1, o] = bf16(relu(b1[o] + Hpart[0]+Hpart[1]+Hpart[2]))
__global__ void k_hprep3(const float* __restrict__ Hpart, const float* __restrict__ b1,
                         bf16* __restrict__ hpadT) {
  __shared__ float T[32][132];
  int n = blockIdx.y, p0 = blockIdx.x * 32;
  int tx = threadIdx.x, ty = threadIdx.y;
  const size_t str = (size_t)KN * KOC * KHW;
  const float* hb = Hpart + (size_t)n * KOC * KHW;
  #pragma unroll
  for (int oc = 0; oc < 16; oc++) {
    int o = oc * 8 + ty;
    size_t off = (size_t)o * KHW + p0 + tx;
    T[tx][o] = fmaxf(hb[off] + hb[str + off] + hb[2 * str + off] + b1[o], 0.0f);
  }
  __syncthreads();
  bf16* hp = hpadT + (size_t)n * KPW * KPW * KOC;
  #pragma unroll
  for (int pc = 0; pc < 4; pc++) {
    int pl = ty * 4 + pc;
    int pp = p0 + pl;
    int yy = pp / KH, xx = pp % KH;
    bf16* row = hp + ((size_t)(yy + 1) * KPW + (xx + 1)) * KOC;
    #pragma unroll
    for (int u = 0; u < 4; u++) row[tx * 4 + u] = __float2bfloat16(T[pl][tx * 4 + u]);
  }
}

// ---------------- conv2f: dy-fused conv2 (K=1152) + bias + shortcut + relu -> out ----------
// 500 blocks = 10n * 50pt (N=32), m204 bijective XCD swizzle (500 = 8*62+4).
// LDS 40KB -> 4 blocks/CU = 1024 slots >= 500 -> single round. Single-__syncthreads protocol.
__global__ __launch_bounds__(256) void k_conv2f(const short* __restrict__ w2p,
                                                const short* __restrict__ hpadT,
                                                const float* __restrict__ Hpart,
                                                const float* __restrict__ b2,
                                                const float* __restrict__ bs,
                                                float* __restrict__ out) {
  __shared__ __align__(16) short smem[20480];  // As[2][8192] | Bs[2][2048] (40 KB)
  short* As = smem;
  short* Bs = smem + 16384;
  int b = blockIdx.x;
  int xcd = b & 7, bi = b >> 3;
  int wgid = (xcd < 4 ? xcd * 63 : 4 * 63 + (xcd - 4) * 62) + bi;   // bijective over 500
  int n = wgid / 50, pt = wgid % 50;
  int p0 = pt * 32;
  int tid = threadIdx.x, lane = tid & 63, wave = tid >> 6;
  int quad = lane >> 4, l15 = lane & 15;
  int wm = (wave & 1) * 64, wn = (wave >> 1) * 16;
  int sk = ((tid & 7) ^ ((tid >> 3) & 7)) * 8;
  int rowg = tid >> 3;                          // 0..31
  const short* hb = hpadT + (size_t)n * KPW * KPW * KOC;
  const short* pA[4];
  #pragma unroll
  for (int g = 0; g < 4; g++)
    pA[g] = w2p + (size_t)(g * 32 + rowg) * (9 * KOC) + sk;
  int prow = p0 + rowg;
  int py = prow / KH, px = prow % KH;
  const short* pB0 = hb + ((size_t)py * KPW + px) * KOC + sk;
  char* lA = (char*)As + tid * 16;
  char* lB = (char*)Bs + tid * 16;
  int bq = (l15 >> 2) & 1;
  int qx = (quad ^ (l15 & 3)) * 8;
  int koff0 = 32 * bq + qx;
  int koff1 = 32 * (1 - bq) + qx;
  f32x4 acc[4] = {};
  const int NS = 18;                            // 3dy * 3dx * (128/64); dy=s/6, dx=(s%6)>>1, kh=(s&1)*64
  gload16(pA[0], lA); gload16(pA[1], lA + 4096);
  gload16(pA[2], lA + 8192); gload16(pA[3], lA + 12288);
  gload16(pB0, lB);
  __syncthreads();                              // buf0 landed
  for (int s = 0; s < NS; s++) {
    int cb = s & 1, nb = cb ^ 1;
    if (s + 1 < NS) {
      int s2 = s + 1;
      int dy = s2 / 6, dxq = (s2 % 6) >> 1, kh = (s2 & 1) * 64;
      int ao = (dy * 3 + dxq) * 128 + kh;
      int bo = (dy * 42 + dxq) * 128 + kh;
      char* la = lA + nb * 16384;               // As buf stride 16 KB
      char* lb = lB + nb * 4096;                // Bs buf stride 4 KB
      gload16(pA[0] + ao, la); gload16(pA[1] + ao, la + 4096);
      gload16(pA[2] + ao, la + 8192); gload16(pA[3] + ao, la + 12288);
      gload16(pB0 + bo, lb);
    }
    const short* Ab = As + cb * 8192;
    const short* Bb = Bs + cb * 2048;
    #pragma unroll
    for (int ks = 0; ks < 2; ks++) {
      int ko = (ks == 0) ? koff0 : koff1;
      short8 av[4], bv;
      #pragma unroll
      for (int t = 0; t < 4; t++) av[t] = *(const short8*)&Ab[(wm + t * 16 + l15) * 64 + ko];
      bv = *(const short8*)&Bb[(wn + l15) * 64 + ko];
      #pragma unroll
      for (int ti = 0; ti < 4; ti++)
        acc[ti] = __builtin_amdgcn_mfma_f32_16x16x32_bf16(av[ti], bv, acc[ti], 0, 0, 0);
    }
    __syncthreads();                            // drains prefetch; fences WAR on cb
  }
  // epilogue: out = relu(acc + b2 + bs + Hpart[3])
  const float* hsc = Hpart + ((size_t)(3 * KN + n)) * KOC * KHW;
  float* ob = out + (size_t)n * KOC * KHW;
  int q = p0 + wn + l15;
  #pragma unroll
  for (int ti = 0; ti < 4; ti++) {
    int o = wm + ti * 16 + quad * 4;
    f32x4 b2v = *(const f32x4*)&b2[o];
    f32x4 bsv = *(const f32x4*)&bs[o];
    #pragma unroll
    for (int r = 0; r < 4; r++) {
      float v = acc[ti][r] + b2v[r] + bsv[r] + hsc[(size_t)(o + r) * KHW + q];
      ob[(size_t)(o + r) * KHW + q] = fmaxf(v, 0.0f);
    }
  }
}

// ---------------- launch ----------------
extern "C" void kernel_launch(void* const* d_in, const int* in_sizes, int n_in,
                              void* d_out, int out_size, void* d_ws, size_t ws_size,
                              hipStream_t stream) {
  const float* feats = (const float*)d_in[0];
  const float* sisms = (const float*)d_in[1];
  const float* w1 = (const float*)d_in[2];
  const float* b1 = (const float*)d_in[3];
  const float* w2 = (const float*)d_in[4];
  const float* b2 = (const float*)d_in[5];
  const float* wsc = (const float*)d_in[6];
  const float* bsc = (const float*)d_in[7];
  float* out = (float*)d_out;

  char* w = (char*)d_ws;
  auto carve = [&](size_t bytes) -> void* {
    void* p = (void*)w;
    w += (bytes + 255) & ~(size_t)255;
    return p;
  };
  bf16* NFT   = (bf16*)carve((size_t)KN * KHW * KC * 2);          // 16.4 MB
  bf16* NFcg  = (bf16*)carve((size_t)KN * KC * KHW * 2);          // 16.4 MB
  bf16* Uc    = (bf16*)carve((size_t)KN * 3 * 128 * 1536 * 2);    // 11.8 MB
  bf16* Usc   = (bf16*)carve((size_t)KN * 128 * 512 * 2);         // 1.3 MB
  bf16* w1s   = (bf16*)carve((size_t)KM * KHW * 2);               // 4.1 MB
  bf16* Zpad  = (bf16*)carve((size_t)KN * KPW * KPW * KC * 2);    // 18.1 MB
  bf16* hpadT = (bf16*)carve((size_t)KN * KPW * KPW * KOC * 2);   // 4.5 MB
  float* Hpart = (float*)carve((size_t)4 * KN * KOC * KHW * 4);   // 32.8 MB
  bf16* w2p   = (bf16*)carve((size_t)KOC * 9 * KOC * 2);
  double* psbuf = (double*)carve((size_t)16 * KN * KHW * 8);      // 2.05 MB
  double* rnorm = (double*)carve((size_t)KN * KHW * 8);
  double* vpp   = (double*)carve((size_t)KN * KC * 50 * 8);       // 2.05 MB
  double* SIV   = (double*)carve((size_t)KN * KC * 8);
  double* cmp   = (double*)carve((size_t)16 * KN * KN * KHW * 8); // 20.5 MB
  double* cm    = (double*)carve((size_t)KN * KN * KHW * 8);
  double* tbuf  = (double*)carve((size_t)KN * KN * 8);
  double* CSAd  = (double*)carve((size_t)KN * KHW * 8);
  float* CSAf   = (float*)carve((size_t)KN * KHW * 4);
  int* idxb     = (int*)carve((size_t)KN * KHW * 4);

  k_zborder<<<513, 256, 0, stream>>>(Zpad, hpadT);

  k_rnormp<<<dim3(63, 16), 256, 0, stream>>>(feats, psbuf);
  k_rnormc<<<63, 256, 0, stream>>>(psbuf, rnorm);
  k_nft<<<dim3(50, 16, KN), dim3(32, 8), 0, stream>>>(feats, rnorm, sisms, NFT, vpp);
  k_sivnorm2<<<KN, 512, 0, stream>>>(vpp, SIV);
  k_cmP<<<dim3(7, 16, KN), 256, 0, stream>>>(feats, SIV, cmp);
  k_cmBN<<<KN * KN, 512, 0, stream>>>(cmp, rnorm, cm);
  k_st<<<KN * KN, 256, 0, stream>>>(cm, tbuf);
  k_csa<<<KN, 256, 0, stream>>>(cm, tbuf, CSAd, CSAf);
  k_rank<<<1000, 256, 0, stream>>>(CSAd, idxb);

  k_prepw1s<<<KM * KHW / 256, 256, 0, stream>>>(w1, wsc, w1s);
  k_prepw2<<<576, 256, 0, stream>>>(w2, w2p);
  k_gath2<<<dim3(50, 16, KN), dim3(32, 8), 0, stream>>>((const short*)NFT, idxb, (short*)NFcg);
  k_zprep<<<KN * KHW * (KC / 4) / 256, 256, 0, stream>>>(NFT, CSAf, Zpad);

  k_gemmU<<<800, 256, 0, stream>>>((const short*)w1s, (const short*)NFcg, Uc, Usc);
  k_convh<<<1000, 256, 0, stream>>>((const short*)Uc, (const short*)Usc,
                                    (const short*)Zpad, Hpart);
  k_hprep3<<<dim3(50, KN), dim3(32, 8), 0, stream>>>(Hpart, b1, hpadT);
  k_conv2f<<<500, 256, 0, stream>>>((const short*)w2p, (const short*)hpadT,
                                    Hpart, b2, bsc, out);
}

// Round 13
// 262.192 us; speedup vs baseline: 1.0490x; 1.0322x over previous
//
#include <hip/hip_runtime.h>
#include <hip/hip_bf16.h>
#include <math.h>

typedef short short8 __attribute__((ext_vector_type(8)));
typedef short short4v __attribute__((ext_vector_type(4)));
typedef float f32x4 __attribute__((ext_vector_type(4)));
typedef __hip_bfloat16 bf16;

// problem constants
#define KN 10
#define KC 512
#define KHW 1600
#define KH 40
#define KOC 128
#define KPW 42   // padded spatial (40+2)
#define KM 1280  // stacked M: 9 conv taps * 128 + 128 shortcut

// direct global->LDS DMA, 16B per lane. LDS dest must be wave-uniform base + lane*16.
__device__ __forceinline__ void gload16(const void* g, void* l) {
  __builtin_amdgcn_global_load_lds(
      (const __attribute__((address_space(1))) unsigned int*)g,
      (__attribute__((address_space(3))) unsigned int*)l, 16, 0, 0);
}

// ---------------- block reduction helpers (fp64) ----------------
__device__ __forceinline__ double blockReduceSumD(double v) {
  __shared__ double tmpS[8];
  int lane = threadIdx.x & 63, wv = threadIdx.x >> 6;
  #pragma unroll
  for (int o = 32; o > 0; o >>= 1) v += __shfl_down(v, o);
  if (lane == 0) tmpS[wv] = v;
  __syncthreads();
  if (threadIdx.x == 0) {
    int nw = (blockDim.x + 63) >> 6;
    double s = 0;
    for (int i = 0; i < nw; i++) s += tmpS[i];
    tmpS[0] = s;
  }
  __syncthreads();
  double r = tmpS[0];
  __syncthreads();
  return r;
}

__device__ __forceinline__ double blockReduceMinD(double v) {
  __shared__ double tmpMn[8];
  int lane = threadIdx.x & 63, wv = threadIdx.x >> 6;
  #pragma unroll
  for (int o = 32; o > 0; o >>= 1) v = fmin(v, __shfl_down(v, o));
  if (lane == 0) tmpMn[wv] = v;
  __syncthreads();
  if (threadIdx.x == 0) {
    int nw = (blockDim.x + 63) >> 6;
    double s = tmpMn[0];
    for (int i = 1; i < nw; i++) s = fmin(s, tmpMn[i]);
    tmpMn[0] = s;
  }
  __syncthreads();
  double r = tmpMn[0];
  __syncthreads();
  return r;
}

__device__ __forceinline__ double blockReduceMaxD(double v) {
  __shared__ double tmpMx[8];
  int lane = threadIdx.x & 63, wv = threadIdx.x >> 6;
  #pragma unroll
  for (int o = 32; o > 0; o >>= 1) v = fmax(v, __shfl_down(v, o));
  if (lane == 0) tmpMx[wv] = v;
  __syncthreads();
  if (threadIdx.x == 0) {
    int nw = (blockDim.x + 63) >> 6;
    double s = tmpMx[0];
    for (int i = 1; i < nw; i++) s = fmax(s, tmpMx[i]);
    tmpMx[0] = s;
  }
  __syncthreads();
  double r = tmpMx[0];
  __syncthreads();
  return r;
}

// ---------------- small chain (fp64 for argsort stability) ----------------

// 16 channel-slices of 32; float4 over k (4 k's per thread, same c-order -> bitwise identical)
__global__ void k_rnormp(const float* __restrict__ feats, double* __restrict__ ps) {
  int t4 = blockIdx.x * 256 + threadIdx.x;     // [0, KN*KHW/4)
  if (t4 >= KN * KHW / 4) return;
  int ci = blockIdx.y;
  int k4 = t4 * 4;
  int n = k4 / KHW, k = k4 % KHW;
  const float* p = feats + (size_t)n * KC * KHW + (size_t)ci * 32 * KHW + k;
  double s0 = 0, s1 = 0, s2 = 0, s3 = 0;
  #pragma unroll
  for (int c = 0; c < 32; ++c) {
    float4 v = *(const float4*)&p[(size_t)c * KHW];
    s0 += (double)v.x * v.x;
    s1 += (double)v.y * v.y;
    s2 += (double)v.z * v.z;
    s3 += (double)v.w * v.w;
  }
  double* pd = ps + (size_t)ci * KN * KHW + (size_t)n * KHW + k;
  pd[0] = s0; pd[1] = s1; pd[2] = s2; pd[3] = s3;
}

__global__ void k_rnormc(const double* __restrict__ ps, double* __restrict__ rnorm) {
  int t = blockIdx.x * 256 + threadIdx.x;
  if (t >= KN * KHW) return;
  double s = 0;
  #pragma unroll
  for (int ci = 0; ci < 16; ci++) s += ps[(size_t)ci * KN * KHW + t];
  double nn = sqrt(s);
  if (nn < 1e-12) nn = 1e-12;
  rnorm[t] = 1.0 / nn;
}

// NFT[n,k,c] = bf16(feats[n,c,k] * rnorm[n,k]); also emits SIV pre-partials
__global__ void k_nft(const float* __restrict__ feats, const double* __restrict__ rnorm,
                      const float* __restrict__ sism, bf16* __restrict__ NFT,
                      double* __restrict__ vpp) {
  __shared__ float T[32][33];
  int n = blockIdx.z, k0 = blockIdx.x * 32, c0 = blockIdx.y * 32;
  int tx = threadIdx.x, ty = threadIdx.y;
  const float* fb = feats + ((size_t)n * KC + c0) * KHW + k0;
  {
    int tid = ty * 32 + tx;
    int cc = tid >> 3;          // 0..31
    int k4 = (tid & 7) * 4;     // 0..28
    float4 v = *(const float4*)&fb[(size_t)cc * KHW + k4];
    T[cc][k4 + 0] = v.x; T[cc][k4 + 1] = v.y;
    T[cc][k4 + 2] = v.z; T[cc][k4 + 3] = v.w;
  }
  __syncthreads();
  bf16* ob = NFT + ((size_t)n * KHW + k0) * KC + c0;
  #pragma unroll
  for (int ii = 0; ii < 4; ii++) {
    int kl = ty * 4 + ii;
    float r = (float)rnorm[n * KHW + k0 + kl];
    ob[(size_t)kl * KC + tx] = __float2bfloat16(T[tx][kl] * r);
  }
  double rs = rnorm[n * KHW + k0 + tx] * (double)sism[n * KHW + k0 + tx];
  #pragma unroll
  for (int ii = 0; ii < 4; ii++) {
    int cl = ty * 4 + ii;
    double v = (double)T[cl][tx] * rs;
    #pragma unroll
    for (int o = 16; o > 0; o >>= 1) v += __shfl_down(v, o, 32);
    if (tx == 0) vpp[((size_t)n * KC + c0 + cl) * 50 + k0 / 32] = v;
  }
}

__global__ void k_sivnorm2(const double* __restrict__ vpp, double* __restrict__ SIV) {
  int n = blockIdx.x, c = threadIdx.x;   // 512 threads
  const double* p = vpp + ((size_t)n * KC + c) * 50;
  double acc = 0;
  #pragma unroll 5
  for (int j = 0; j < 50; j++) acc += p[j];
  acc /= (double)KHW;
  double s2 = blockReduceSumD(acc * acc);
  double nn = sqrt(s2);
  if (nn < 1e-12) nn = 1e-12;
  SIV[n * KC + c] = acc / nn;
}

// 16 channel-slices of 32: 1120 blocks
__global__ void k_cmP(const float* __restrict__ feats, const double* __restrict__ SIV,
                      double* __restrict__ cmp) {
  __shared__ double sv[KN][32];
  int kc = blockIdx.x, ci = blockIdx.y, n = blockIdx.z;
  for (int t = threadIdx.x; t < KN * 32; t += 256) {
    int m = t / 32, c = t % 32;
    sv[m][c] = SIV[m * KC + ci * 32 + c];
  }
  __syncthreads();
  int k = kc * 256 + threadIdx.x;
  if (k >= KHW) return;
  const float* f = feats + ((size_t)n * KC + ci * 32) * KHW + k;
  double acc[KN];
  #pragma unroll
  for (int m = 0; m < KN; m++) acc[m] = 0.0;
  for (int c = 0; c < 32; ++c) {
    double fv = f[(size_t)c * KHW];
    #pragma unroll
    for (int m = 0; m < KN; m++) acc[m] += fv * sv[m][c];
  }
  const size_t str = (size_t)KN * KN * KHW;
  #pragma unroll
  for (int m = 0; m < KN; m++)
    cmp[(size_t)ci * str + ((size_t)n * KN + m) * KHW + k] = acc[m];
}

// fused cmB + cmnorm
__global__ void k_cmBN(const double* __restrict__ cmp, const double* __restrict__ rnorm,
                       double* __restrict__ cm) {
  int b = blockIdx.x;                       // 100 = n*KN + m
  int n = b / KN;
  const size_t str = (size_t)KN * KN * KHW;
  const size_t rb = (size_t)b * KHW;
  double v[4];
  int cnt = 0;
  double ss = 0;
  for (int k = threadIdx.x; k < KHW; k += 512) {
    double s = 0;
    #pragma unroll
    for (int ci = 0; ci < 16; ci++) s += cmp[ci * str + rb + k];
    s *= rnorm[n * KHW + k];
    v[cnt++] = s;
    ss += s * s;
  }
  ss = blockReduceSumD(ss);
  double nn = sqrt(ss);
  if (nn < 1e-12) nn = 1e-12;
  double rn = 1.0 / nn;
  cnt = 0;
  for (int k = threadIdx.x; k < KHW; k += 512) cm[rb + k] = v[cnt++] * rn;
}

__global__ void k_st(const double* __restrict__ cm, double* __restrict__ tbuf) {
  int b = blockIdx.x;
  int n = b / KN, m = b % KN;
  const double* base = cm + (size_t)n * KN * KHW;
  double acc = 0;
  for (int k = threadIdx.x; k < KHW; k += 256) {
    double S = 0;
    #pragma unroll
    for (int mm = 0; mm < KN; mm++) S += base[(size_t)mm * KHW + k];
    acc += base[(size_t)m * KHW + k] * S;
  }
  acc = blockReduceSumD(acc);
  if (threadIdx.x == 0) tbuf[b] = acc;
}

__global__ void k_csa(const double* __restrict__ cm, const double* __restrict__ tbuf,
                      double* __restrict__ CSAd, float* __restrict__ CSAf) {
  __shared__ double w[KN];
  int n = blockIdx.x, tid = threadIdx.x;
  if (tid == 0) {
    double v[KN], mx = -1e300;
    #pragma unroll
    for (int m = 0; m < KN; m++) { v[m] = tbuf[n * KN + m]; mx = fmax(mx, v[m]); }
    double s = 0;
    #pragma unroll
    for (int m = 0; m < KN; m++) { v[m] = exp(v[m] - mx); s += v[m]; }
    #pragma unroll
    for (int m = 0; m < KN; m++) w[m] = v[m] / s;
  }
  __syncthreads();
  double v[7];
  int cnt = 0;
  double lmin = 1e300, lmax = -1e300;
  for (int k = tid; k < KHW; k += 256) {
    double a = 0;
    #pragma unroll
    for (int m = 0; m < KN; m++) a += cm[((size_t)n * KN + m) * KHW + k] * w[m];
    v[cnt++] = a;
    lmin = fmin(lmin, a);
    lmax = fmax(lmax, a);
  }
  double mn = blockReduceMinD(lmin);
  double mx = blockReduceMaxD(lmax);
  double inv = 1.0 / (mx - mn + 1e-12);
  cnt = 0;
  for (int k = tid; k < KHW; k += 256) {
    double nv = (v[cnt++] - mn) * inv;
    CSAd[(size_t)n * KHW + k] = nv;
    CSAf[(size_t)n * KHW + k] = (float)nv;
  }
}

// rank-based stable descending argsort: idx[rank[i]] = i
__global__ void k_rank(const double* __restrict__ CSAd, int* __restrict__ idx) {
  __shared__ double key[KHW];
  int b = blockIdx.x;
  int n = b / 100, it = b % 100;
  const double* src = CSAd + (size_t)n * KHW;
  for (int j = threadIdx.x; j < KHW; j += 256) key[j] = src[j];
  __syncthreads();
  int wave = threadIdx.x >> 6, lane = threadIdx.x & 63;
  int i0 = it * 16 + wave * 4;
  double ki[4];
  #pragma unroll
  for (int ii = 0; ii < 4; ii++) ki[ii] = key[i0 + ii];
  int r[4] = {0, 0, 0, 0};
  #pragma unroll
  for (int q = 0; q < 25; q++) {
    int j = q * 64 + lane;
    double kj = key[j];
    #pragma unroll
    for (int ii = 0; ii < 4; ii++) {
      int i = i0 + ii;
      r[ii] += (kj > ki[ii]) || (kj == ki[ii] && j < i);
    }
  }
  #pragma unroll
  for (int ii = 0; ii < 4; ii++) {
    int v = r[ii];
    #pragma unroll
    for (int o = 32; o > 0; o >>= 1) v += __shfl_down(v, o);
    if (lane == 0) idx[n * KHW + v] = i0 + ii;
  }
}

// ---------------- fused input prep: w1s stack + w2 repack + pad borders ----------------
// blocks [0,8000): prepw1s; [8000,8576): prepw2; [8576,9089): zborder. All input-only.
__global__ void k_prep(const float* __restrict__ w1, const float* __restrict__ wsc,
                       const float* __restrict__ w2,
                       bf16* __restrict__ w1s, bf16* __restrict__ w2p,
                       bf16* __restrict__ Zpad, bf16* __restrict__ hpadT) {
  int b = blockIdx.x;
  if (b < 8000) {
    int t = b * 256 + threadIdx.x;           // over KM*KHW
    int m = t / KHW, i = t % KHW;
    int tau = m >> 7, o = m & 127;
    float v = (tau < 9) ? w1[((size_t)o * KHW + i) * 9 + tau]
                        : wsc[(size_t)o * KHW + i];
    w1s[t] = __float2bfloat16(v);
  } else if (b < 8576) {
    int t = (b - 8000) * 256 + threadIdx.x;
    if (t >= KOC * 9 * KOC) return;
    int o = t / (9 * KOC), r = t % (9 * KOC);
    int s = r / KOC, i = r % KOC;
    w2p[t] = __float2bfloat16(w2[(size_t)o * 9 * KOC + (size_t)i * 9 + s]);
  } else {
    int t = (b - 8576) * 256 + threadIdx.x;
    const int ZW = KN * 164 * (KC / 8);      // 104960
    const int HWm = KN * 164 * (KOC / 8);    // 26240
    int bb;
    if (t < ZW) {
      int n = t / (164 * 64), r = t % (164 * 64);
      bb = r / 64;
      int c8 = r % 64;
      int y, x;
      if (bb < 42) { y = 0; x = bb; }
      else if (bb < 84) { y = 41; x = bb - 42; }
      else if (bb < 124) { y = bb - 84 + 1; x = 0; }
      else { y = bb - 124 + 1; x = 41; }
      short8 z = {};
      *(short8*)((short*)Zpad + ((size_t)n * KPW * KPW + (size_t)y * KPW + x) * KC + c8 * 8) = z;
    } else if (t < ZW + HWm) {
      int u = t - ZW;
      int n = u / (164 * 16), r = u % (164 * 16);
      bb = r / 16;
      int c8 = r % 16;
      int y, x;
      if (bb < 42) { y = 0; x = bb; }
      else if (bb < 84) { y = 41; x = bb - 42; }
      else if (bb < 124) { y = bb - 84 + 1; x = 0; }
      else { y = bb - 124 + 1; x = 41; }
      short8 z = {};
      *(short8*)((short*)hpadT + ((size_t)n * KPW * KPW + (size_t)y * KPW + x) * KOC + c8 * 8) = z;
    }
  }
}

// ---------------- fused gather + Zpad prep (both consume NFT after rank; independent) -----
// blocks [0,8000): gath2 (NFcg); [8000,16000): zprep (Zpad). blockDim (32,8).
__global__ void k_gz(const short* __restrict__ NFT, const int* __restrict__ idx,
                     const float* __restrict__ CSAf,
                     short* __restrict__ NFcg, bf16* __restrict__ Zpad) {
  __shared__ short T[32][33];
  int b = blockIdx.x;
  int tx = threadIdx.x, ty = threadIdx.y;
  if (b < 8000) {
    int n = b / 800, r = b % 800;
    int c0 = (r / 50) * 32, i0 = (r % 50) * 32;
    #pragma unroll
    for (int ii = 0; ii < 4; ii++) {
      int row = ty * 4 + ii;
      int id = idx[n * KHW + i0 + row];
      T[row][tx] = NFT[((size_t)n * KHW + id) * KC + c0 + tx];
    }
    __syncthreads();
    #pragma unroll
    for (int ii = 0; ii < 4; ii++) {
      int cl = ty * 4 + ii;
      NFcg[((size_t)n * KC + c0 + cl) * KHW + i0 + tx] = T[tx][cl];
    }
  } else {
    int t = (b - 8000) * 256 + (ty * 32 + tx);   // over KN*KHW*KC/4
    const int per_n = KHW * (KC / 4);
    int n = t / per_n, r = t % per_n;
    int p = r / (KC / 4), cq = r % (KC / 4);
    float cs = CSAf[n * KHW + p];
    const short* src = (const short*)(NFT + ((size_t)n * KHW + p) * KC) + cq * 4;
    short4v v = *(const short4v*)src;
    short4v o;
    #pragma unroll
    for (int j = 0; j < 4; j++) {
      short s = v[j];
      bf16 hb = *reinterpret_cast<bf16*>(&s);
      bf16 res = __float2bfloat16(__bfloat162float(hb) * cs);
      o[j] = *reinterpret_cast<short*>(&res);
    }
    int y = p / KH, x = p % KH;
    short* dst = (short*)(Zpad + ((size_t)n * KPW * KPW + (size_t)(y + 1) * KPW + (x + 1)) * KC) + cq * 4;
    *(short4v*)dst = o;
  }
}

// ---------------- GEMM1: U = w1s x NFcg; pipelined BK=64, single-__syncthreads protocol ----
__global__ __launch_bounds__(256) void k_gemmU(const short* __restrict__ w1s,
                                               const short* __restrict__ NFcg,
                                               bf16* __restrict__ Uc,
                                               bf16* __restrict__ Usc) {
  __shared__ __align__(16) short smem[24576];  // As[2][4096] | Bs[2][8192] (48 KB); reused as Cs[64][136]
  short* As = smem;
  short* Bs = smem + 8192;
  short* Cs = smem;
  int b = blockIdx.x;
  int workid = (b & 7) * 100 + (b >> 3);       // bijective, 800 % 8 == 0
  int pair = workid / 20;
  int th = workid % 20;
  int n = pair >> 2, c0 = (pair & 3) * 128;
  int tau = th >> 1, half = th & 1;
  int m0 = tau * 128 + half * 64;
  int tid = threadIdx.x, lane = tid & 63, wave = tid >> 6;
  int quad = lane >> 4, l15 = lane & 15;
  int wm = (wave & 1) * 32, wn = (wave >> 1) * 64;
  int sk = ((tid & 7) ^ ((tid >> 3) & 7)) * 8;
  int rowg = tid >> 3;
  const short* Bb = NFcg + (size_t)n * KC * KHW;
  const short* pA[2];
  #pragma unroll
  for (int g = 0; g < 2; g++)
    pA[g] = w1s + (size_t)(m0 + g * 32 + rowg) * KHW + sk;
  const short* pB[4];
  #pragma unroll
  for (int g = 0; g < 4; g++)
    pB[g] = Bb + (size_t)(c0 + g * 32 + rowg) * KHW + sk;
  char* lA = (char*)As + tid * 16;
  char* lB = (char*)Bs + tid * 16;
  int bq = (l15 >> 2) & 1;
  int qx = (quad ^ (l15 & 3)) * 8;
  int koff0 = 32 * bq + qx;
  int koff1 = 32 * (1 - bq) + qx;
  f32x4 acc[2][4] = {};
  gload16(pA[0], lA); gload16(pA[1], lA + 4096);
  gload16(pB[0], lB); gload16(pB[1], lB + 4096);
  gload16(pB[2], lB + 8192); gload16(pB[3], lB + 12288);
  __syncthreads();                             // buf0 landed for all waves
  const int NS = 25;
  for (int s = 0; s < NS; s++) {
    int cb = s & 1, nb = cb ^ 1;
    if (s + 1 < NS) {
      int off = (s + 1) * 64;
      char* la = lA + nb * 8192;
      char* lb = lB + nb * 16384;
      gload16(pA[0] + off, la); gload16(pA[1] + off, la + 4096);
      gload16(pB[0] + off, lb); gload16(pB[1] + off, lb + 4096);
      gload16(pB[2] + off, lb + 8192); gload16(pB[3] + off, lb + 12288);
    }
    const short* Ab = As + cb * 4096;
    const short* Bbf = Bs + cb * 8192;
    #pragma unroll
    for (int ks = 0; ks < 2; ks++) {
      int ko = (ks == 0) ? koff0 : koff1;
      short8 av[2], bv[4];
      #pragma unroll
      for (int t = 0; t < 2; t++) av[t] = *(const short8*)&Ab[(wm + t * 16 + l15) * 64 + ko];
      #pragma unroll
      for (int t = 0; t < 4; t++) bv[t] = *(const short8*)&Bbf[(wn + t * 16 + l15) * 64 + ko];
      #pragma unroll
      for (int ti = 0; ti < 2; ti++)
        #pragma unroll
        for (int tj = 0; tj < 4; tj++)
          acc[ti][tj] = __builtin_amdgcn_mfma_f32_16x16x32_bf16(av[ti], bv[tj], acc[ti][tj], 0, 0, 0);
    }
    __syncthreads();                           // drains prefetch; fences WAR on cb
  }
  #pragma unroll
  for (int ti = 0; ti < 2; ti++) {
    int lr = wm + ti * 16 + quad * 4;
    #pragma unroll
    for (int tj = 0; tj < 4; tj++) {
      int lc = wn + tj * 16 + l15;
      #pragma unroll
      for (int r = 0; r < 4; r++)
        *(bf16*)&Cs[(lr + r) * 136 + lc] = __float2bfloat16(acc[ti][tj][r]);
    }
  }
  __syncthreads();
  int dyq = tau / 3, dxq = tau % 3;
  #pragma unroll
  for (int pass = 0; pass < 4; pass++) {
    int row = pass * 16 + (tid >> 4);
    int col = (tid & 15) * 8;
    if (tau < 9) {
      *(float4*)&Uc[((size_t)((n * 3 + dyq) * 128 + half * 64 + row)) * 1536 + dxq * 512 + c0 + col] =
          *(const float4*)&Cs[row * 136 + col];
    } else {
      *(float4*)&Usc[((size_t)(n * 128 + half * 64 + row)) * 512 + c0 + col] =
          *(const float4*)&Cs[row * 136 + col];
    }
  }
}

// ---------------- convh: dy-split pipelined GEMM, single-__syncthreads protocol ----------
// 1000 blocks: conv (long, NS=24) at blockIdx 0..749 (bijective m204 swizzle over 750),
// shortcut (short, NS=8) at 750..999 so the straggler round consists of SHORT blocks.
__global__ __launch_bounds__(256) void k_convh(const short* __restrict__ Uc,
                                               const short* __restrict__ Usc,
                                               const short* __restrict__ Zpad,
                                               float* __restrict__ Hpart) {
  __shared__ __align__(16) short smem[24576];  // As[2][8192] | Bs[2][4096]  (48 KB)
  short* As = smem;
  short* Bs = smem + 16384;
  int b = blockIdx.x;
  bool isconv = (b < 750);
  int n, dy, pt;
  if (isconv) {
    int xcd = b & 7, bi = b >> 3;
    int wgid = (xcd < 6 ? xcd * 94 : 6 * 94 + (xcd - 6) * 93) + bi;   // bijective over 750
    n = wgid / 75;
    int rest = wgid % 75;
    dy = rest / 25; pt = rest % 25;
  } else {
    int u = b - 750;
    n = u / 25; pt = u % 25; dy = 3;
  }
  int p0 = pt * 64;
  int tid = threadIdx.x, lane = tid & 63, wave = tid >> 6;
  int quad = lane >> 4, l15 = lane & 15;
  int wm = (wave & 1) * 64, wn = (wave >> 1) * 32;
  int sk = ((tid & 7) ^ ((tid >> 3) & 7)) * 8;
  int rowg = tid >> 3;
  const short* Zb = Zpad + (size_t)n * KPW * KPW * KC;
  const short* Abase = isconv ? Uc + ((size_t)((n * 3 + dy) * 128)) * 1536
                              : Usc + ((size_t)(n * 128)) * 512;
  int astr = isconv ? 1536 : 512;
  const short* pA[4];
  #pragma unroll
  for (int g = 0; g < 4; g++)
    pA[g] = Abase + (size_t)(g * 32 + rowg) * astr + sk;
  const short* pB[2];
  #pragma unroll
  for (int g = 0; g < 2; g++) {
    int p = p0 + g * 32 + rowg;
    int y = p / KH, x = p % KH;
    int yy = isconv ? (y + dy) : (y + 1);
    int xx = isconv ? x : (x + 1);
    pB[g] = Zb + ((size_t)yy * KPW + xx) * KC + sk;
  }
  char* lA = (char*)As + tid * 16;
  char* lB = (char*)Bs + tid * 16;
  int NS = isconv ? 24 : 8;
  int bq = (l15 >> 2) & 1;
  int qx = (quad ^ (l15 & 3)) * 8;
  int koff0 = 32 * bq + qx;
  int koff1 = 32 * (1 - bq) + qx;
  f32x4 acc[4][2] = {};
  gload16(pA[0], lA); gload16(pA[1], lA + 4096);
  gload16(pA[2], lA + 8192); gload16(pA[3], lA + 12288);
  gload16(pB[0], lB); gload16(pB[1], lB + 4096);
  __syncthreads();                             // buf0 landed
  for (int s = 0; s < NS; s++) {
    int cb = s & 1, nb = cb ^ 1;
    if (s + 1 < NS) {
      int off = (s + 1) * 64;
      char* la = lA + nb * 16384;
      char* lb = lB + nb * 8192;
      gload16(pA[0] + off, la); gload16(pA[1] + off, la + 4096);
      gload16(pA[2] + off, la + 8192); gload16(pA[3] + off, la + 12288);
      gload16(pB[0] + off, lb); gload16(pB[1] + off, lb + 4096);
    }
    const short* Ab = As + cb * 8192;
    const short* Bb = Bs + cb * 4096;
    #pragma unroll
    for (int ks = 0; ks < 2; ks++) {
      int ko = (ks == 0) ? koff0 : koff1;
      short8 av[4], bv[2];
      #pragma unroll
      for (int t = 0; t < 4; t++) av[t] = *(const short8*)&Ab[(wm + t * 16 + l15) * 64 + ko];
      #pragma unroll
      for (int t = 0; t < 2; t++) bv[t] = *(const short8*)&Bb[(wn + t * 16 + l15) * 64 + ko];
      #pragma unroll
      for (int ti = 0; ti < 4; ti++)
        #pragma unroll
        for (int tj = 0; tj < 2; tj++)
          acc[ti][tj] = __builtin_amdgcn_mfma_f32_16x16x32_bf16(av[ti], bv[tj], acc[ti][tj], 0, 0, 0);
    }
    __syncthreads();                           // drains prefetch; fences WAR on cb
  }
  float* cbp = Hpart + ((size_t)(dy * KN + n)) * KOC * KHW;
  #pragma unroll
  for (int ti = 0; ti < 4; ti++) {
    int o = wm + ti * 16 + quad * 4;
    #pragma unroll
    for (int tj = 0; tj < 2; tj++) {
      int q = p0 + wn + tj * 16 + l15;
      #pragma unroll
      for (int r = 0; r < 4; r++)
        cbp[(size_t)(o + r) * KHW + q] = acc[ti][tj][r];
    }
  }
}

// hpadT[n, y+1, x+1, o] = bf16(relu(b1[o] + Hpart[0]+Hpart[1]+Hpart[2]))
__global__ void k_hprep3(const float* __restrict__ Hpart, const float* __restrict__ b1,
                         bf16* __restrict__ hpadT) {
  __shared__ float T[32][132];
  int n = blockIdx.y, p0 = blockIdx.x * 32;
  int tx = threadIdx.x, ty = threadIdx.y;
  const size_t str = (size_t)KN * KOC * KHW;
  const float* hb = Hpart + (size_t)n * KOC * KHW;
  #pragma unroll
  for (int oc = 0; oc < 16; oc++) {
    int o = oc * 8 + ty;
    size_t off = (size_t)o * KHW + p0 + tx;
    T[tx][o] = fmaxf(hb[off] + hb[str + off] + hb[2 * str + off] + b1[o], 0.0f);
  }
  __syncthreads();
  bf16* hp = hpadT + (size_t)n * KPW * KPW * KOC;
  #pragma unroll
  for (int pc = 0; pc < 4; pc++) {
    int pl = ty * 4 + pc;
    int pp = p0 + pl;
    int yy = pp / KH, xx = pp % KH;
    bf16* row = hp + ((size_t)(yy + 1) * KPW + (xx + 1)) * KOC;
    #pragma unroll
    for (int u = 0; u < 4; u++) row[tx * 4 + u] = __float2bfloat16(T[pl][tx * 4 + u]);
  }
}

// ---------------- conv2f: dy-fused conv2 (K=1152) + bias + shortcut + relu -> out ----------
// 500 blocks = 10n * 50pt (N=32), m204 bijective XCD swizzle (500 = 8*62+4).
// LDS 40KB -> 4 blocks/CU = 1024 slots >= 500 -> single round. Single-__syncthreads protocol.
__global__ __launch_bounds__(256) void k_conv2f(const short* __restrict__ w2p,
                                                const short* __restrict__ hpadT,
                                                const float* __restrict__ Hpart,
                                                const float* __restrict__ b2,
                                                const float* __restrict__ bs,
                                                float* __restrict__ out) {
  __shared__ __align__(16) short smem[20480];  // As[2][8192] | Bs[2][2048] (40 KB)
  short* As = smem;
  short* Bs = smem + 16384;
  int b = blockIdx.x;
  int xcd = b & 7, bi = b >> 3;
  int wgid = (xcd < 4 ? xcd * 63 : 4 * 63 + (xcd - 4) * 62) + bi;   // bijective over 500
  int n = wgid / 50, pt = wgid % 50;
  int p0 = pt * 32;
  int tid = threadIdx.x, lane = tid & 63, wave = tid >> 6;
  int quad = lane >> 4, l15 = lane & 15;
  int wm = (wave & 1) * 64, wn = (wave >> 1) * 16;
  int sk = ((tid & 7) ^ ((tid >> 3) & 7)) * 8;
  int rowg = tid >> 3;                          // 0..31
  const short* hb = hpadT + (size_t)n * KPW * KPW * KOC;
  const short* pA[4];
  #pragma unroll
  for (int g = 0; g < 4; g++)
    pA[g] = w2p + (size_t)(g * 32 + rowg) * (9 * KOC) + sk;
  int prow = p0 + rowg;
  int py = prow / KH, px = prow % KH;
  const short* pB0 = hb + ((size_t)py * KPW + px) * KOC + sk;
  char* lA = (char*)As + tid * 16;
  char* lB = (char*)Bs + tid * 16;
  int bq = (l15 >> 2) & 1;
  int qx = (quad ^ (l15 & 3)) * 8;
  int koff0 = 32 * bq + qx;
  int koff1 = 32 * (1 - bq) + qx;
  f32x4 acc[4] = {};
  const int NS = 18;                            // 3dy * 3dx * (128/64); dy=s/6, dx=(s%6)>>1, kh=(s&1)*64
  gload16(pA[0], lA); gload16(pA[1], lA + 4096);
  gload16(pA[2], lA + 8192); gload16(pA[3], lA + 12288);
  gload16(pB0, lB);
  __syncthreads();                              // buf0 landed
  for (int s = 0; s < NS; s++) {
    int cb = s & 1, nb = cb ^ 1;
    if (s + 1 < NS) {
      int s2 = s + 1;
      int dy = s2 / 6, dxq = (s2 % 6) >> 1, kh = (s2 & 1) * 64;
      int ao = (dy * 3 + dxq) * 128 + kh;
      int bo = (dy * 42 + dxq) * 128 + kh;
      char* la = lA + nb * 16384;               // As buf stride 16 KB
      char* lb = lB + nb * 4096;                // Bs buf stride 4 KB
      gload16(pA[0] + ao, la); gload16(pA[1] + ao, la + 4096);
      gload16(pA[2] + ao, la + 8192); gload16(pA[3] + ao, la + 12288);
      gload16(pB0 + bo, lb);
    }
    const short* Ab = As + cb * 8192;
    const short* Bb = Bs + cb * 2048;
    #pragma unroll
    for (int ks = 0; ks < 2; ks++) {
      int ko = (ks == 0) ? koff0 : koff1;
      short8 av[4], bv;
      #pragma unroll
      for (int t = 0; t < 4; t++) av[t] = *(const short8*)&Ab[(wm + t * 16 + l15) * 64 + ko];
      bv = *(const short8*)&Bb[(wn + l15) * 64 + ko];
      #pragma unroll
      for (int ti = 0; ti < 4; ti++)
        acc[ti] = __builtin_amdgcn_mfma_f32_16x16x32_bf16(av[ti], bv, acc[ti], 0, 0, 0);
    }
    __syncthreads();                            // drains prefetch; fences WAR on cb
  }
  // epilogue: out = relu(acc + b2 + bs + Hpart[3])
  const float* hsc = Hpart + ((size_t)(3 * KN + n)) * KOC * KHW;
  float* ob = out + (size_t)n * KOC * KHW;
  int q = p0 + wn + l15;
  #pragma unroll
  for (int ti = 0; ti < 4; ti++) {
    int o = wm + ti * 16 + quad * 4;
    f32x4 b2v = *(const f32x4*)&b2[o];
    f32x4 bsv = *(const f32x4*)&bs[o];
    #pragma unroll
    for (int r = 0; r < 4; r++) {
      float v = acc[ti][r] + b2v[r] + bsv[r] + hsc[(size_t)(o + r) * KHW + q];
      ob[(size_t)(o + r) * KHW + q] = fmaxf(v, 0.0f);
    }
  }
}

// ---------------- launch ----------------
extern "C" void kernel_launch(void* const* d_in, const int* in_sizes, int n_in,
                              void* d_out, int out_size, void* d_ws, size_t ws_size,
                              hipStream_t stream) {
  const float* feats = (const float*)d_in[0];
  const float* sisms = (const float*)d_in[1];
  const float* w1 = (const float*)d_in[2];
  const float* b1 = (const float*)d_in[3];
  const float* w2 = (const float*)d_in[4];
  const float* b2 = (const float*)d_in[5];
  const float* wsc = (const float*)d_in[6];
  const float* bsc = (const float*)d_in[7];
  float* out = (float*)d_out;

  char* w = (char*)d_ws;
  auto carve = [&](size_t bytes) -> void* {
    void* p = (void*)w;
    w += (bytes + 255) & ~(size_t)255;
    return p;
  };
  bf16* NFT   = (bf16*)carve((size_t)KN * KHW * KC * 2);          // 16.4 MB
  bf16* NFcg  = (bf16*)carve((size_t)KN * KC * KHW * 2);          // 16.4 MB
  bf16* Uc    = (bf16*)carve((size_t)KN * 3 * 128 * 1536 * 2);    // 11.8 MB
  bf16* Usc   = (bf16*)carve((size_t)KN * 128 * 512 * 2);         // 1.3 MB
  bf16* w1s   = (bf16*)carve((size_t)KM * KHW * 2);               // 4.1 MB
  bf16* Zpad  = (bf16*)carve((size_t)KN * KPW * KPW * KC * 2);    // 18.1 MB
  bf16* hpadT = (bf16*)carve((size_t)KN * KPW * KPW * KOC * 2);   // 4.5 MB
  float* Hpart = (float*)carve((size_t)4 * KN * KOC * KHW * 4);   // 32.8 MB
  bf16* w2p   = (bf16*)carve((size_t)KOC * 9 * KOC * 2);
  double* psbuf = (double*)carve((size_t)16 * KN * KHW * 8);      // 2.05 MB
  double* rnorm = (double*)carve((size_t)KN * KHW * 8);
  double* vpp   = (double*)carve((size_t)KN * KC * 50 * 8);       // 2.05 MB
  double* SIV   = (double*)carve((size_t)KN * KC * 8);
  double* cmp   = (double*)carve((size_t)16 * KN * KN * KHW * 8); // 20.5 MB
  double* cm    = (double*)carve((size_t)KN * KN * KHW * 8);
  double* tbuf  = (double*)carve((size_t)KN * KN * 8);
  double* CSAd  = (double*)carve((size_t)KN * KHW * 8);
  float* CSAf   = (float*)carve((size_t)KN * KHW * 4);
  int* idxb     = (int*)carve((size_t)KN * KHW * 4);

  k_prep<<<9089, 256, 0, stream>>>(w1, wsc, w2, w1s, w2p, Zpad, hpadT);

  k_rnormp<<<dim3(16, 16), 256, 0, stream>>>(feats, psbuf);
  k_rnormc<<<63, 256, 0, stream>>>(psbuf, rnorm);
  k_nft<<<dim3(50, 16, KN), dim3(32, 8), 0, stream>>>(feats, rnorm, sisms, NFT, vpp);
  k_sivnorm2<<<KN, 512, 0, stream>>>(vpp, SIV);
  k_cmP<<<dim3(7, 16, KN), 256, 0, stream>>>(feats, SIV, cmp);
  k_cmBN<<<KN * KN, 512, 0, stream>>>(cmp, rnorm, cm);
  k_st<<<KN * KN, 256, 0, stream>>>(cm, tbuf);
  k_csa<<<KN, 256, 0, stream>>>(cm, tbuf, CSAd, CSAf);
  k_rank<<<1000, 256, 0, stream>>>(CSAd, idxb);

  k_gz<<<16000, dim3(32, 8), 0, stream>>>((const short*)NFT, idxb, CSAf,
                                          (short*)NFcg, Zpad);

  k_gemmU<<<800, 256, 0, stream>>>((const short*)w1s, (const short*)NFcg, Uc, Usc);
  k_convh<<<1000, 256, 0, stream>>>((const short*)Uc, (const short*)Usc,
                                    (const short*)Zpad, Hpart);
  k_hprep3<<<dim3(50, KN), dim3(32, 8), 0, stream>>>(Hpart, b1, hpadT);
  k_conv2f<<<500, 256, 0, stream>>>((const short*)w2p, (const short*)hpadT,
                                    Hpart, b2, bsc, out);
}

// Round 14
// 248.505 us; speedup vs baseline: 1.1067x; 1.0551x over previous
//
#include <hip/hip_runtime.h>
#include <hip/hip_bf16.h>
#include <math.h>

typedef short short8 __attribute__((ext_vector_type(8)));
typedef short short4v __attribute__((ext_vector_type(4)));
typedef float f32x4 __attribute__((ext_vector_type(4)));
typedef __hip_bfloat16 bf16;

// problem constants
#define KN 10
#define KC 512
#define KHW 1600
#define KH 40
#define KOC 128
#define KPW 42   // padded spatial (40+2)
#define KM 1280  // stacked M: 9 conv taps * 128 + 128 shortcut

// direct global->LDS DMA, 16B per lane. LDS dest must be wave-uniform base + lane*16.
__device__ __forceinline__ void gload16(const void* g, void* l) {
  __builtin_amdgcn_global_load_lds(
      (const __attribute__((address_space(1))) unsigned int*)g,
      (__attribute__((address_space(3))) unsigned int*)l, 16, 0, 0);
}

// ---------------- block reduction helpers (fp64) ----------------
__device__ __forceinline__ double blockReduceSumD(double v) {
  __shared__ double tmpS[8];
  int lane = threadIdx.x & 63, wv = threadIdx.x >> 6;
  #pragma unroll
  for (int o = 32; o > 0; o >>= 1) v += __shfl_down(v, o);
  if (lane == 0) tmpS[wv] = v;
  __syncthreads();
  if (threadIdx.x == 0) {
    int nw = (blockDim.x + 63) >> 6;
    double s = 0;
    for (int i = 0; i < nw; i++) s += tmpS[i];
    tmpS[0] = s;
  }
  __syncthreads();
  double r = tmpS[0];
  __syncthreads();
  return r;
}

__device__ __forceinline__ double blockReduceMinD(double v) {
  __shared__ double tmpMn[8];
  int lane = threadIdx.x & 63, wv = threadIdx.x >> 6;
  #pragma unroll
  for (int o = 32; o > 0; o >>= 1) v = fmin(v, __shfl_down(v, o));
  if (lane == 0) tmpMn[wv] = v;
  __syncthreads();
  if (threadIdx.x == 0) {
    int nw = (blockDim.x + 63) >> 6;
    double s = tmpMn[0];
    for (int i = 1; i < nw; i++) s = fmin(s, tmpMn[i]);
    tmpMn[0] = s;
  }
  __syncthreads();
  double r = tmpMn[0];
  __syncthreads();
  return r;
}

__device__ __forceinline__ double blockReduceMaxD(double v) {
  __shared__ double tmpMx[8];
  int lane = threadIdx.x & 63, wv = threadIdx.x >> 6;
  #pragma unroll
  for (int o = 32; o > 0; o >>= 1) v = fmax(v, __shfl_down(v, o));
  if (lane == 0) tmpMx[wv] = v;
  __syncthreads();
  if (threadIdx.x == 0) {
    int nw = (blockDim.x + 63) >> 6;
    double s = tmpMx[0];
    for (int i = 1; i < nw; i++) s = fmax(s, tmpMx[i]);
    tmpMx[0] = s;
  }
  __syncthreads();
  double r = tmpMx[0];
  __syncthreads();
  return r;
}

// ---------------- small chain (fp64 for argsort stability) ----------------

// 16 channel-slices of 32; float4 over k (4 k's per thread, same c-order -> bitwise identical)
__global__ void k_rnormp(const float* __restrict__ feats, double* __restrict__ ps) {
  int t4 = blockIdx.x * 256 + threadIdx.x;     // [0, KN*KHW/4)
  if (t4 >= KN * KHW / 4) return;
  int ci = blockIdx.y;
  int k4 = t4 * 4;
  int n = k4 / KHW, k = k4 % KHW;
  const float* p = feats + (size_t)n * KC * KHW + (size_t)ci * 32 * KHW + k;
  double s0 = 0, s1 = 0, s2 = 0, s3 = 0;
  #pragma unroll
  for (int c = 0; c < 32; ++c) {
    float4 v = *(const float4*)&p[(size_t)c * KHW];
    s0 += (double)v.x * v.x;
    s1 += (double)v.y * v.y;
    s2 += (double)v.z * v.z;
    s3 += (double)v.w * v.w;
  }
  double* pd = ps + (size_t)ci * KN * KHW + (size_t)n * KHW + k;
  pd[0] = s0; pd[1] = s1; pd[2] = s2; pd[3] = s3;
}

__global__ void k_rnormc(const double* __restrict__ ps, double* __restrict__ rnorm) {
  int t = blockIdx.x * 256 + threadIdx.x;
  if (t >= KN * KHW) return;
  double s = 0;
  #pragma unroll
  for (int ci = 0; ci < 16; ci++) s += ps[(size_t)ci * KN * KHW + t];
  double nn = sqrt(s);
  if (nn < 1e-12) nn = 1e-12;
  rnorm[t] = 1.0 / nn;
}

// NFT[n,k,c] = bf16(feats[n,c,k] * rnorm[n,k]); also emits SIV pre-partials
__global__ void k_nft(const float* __restrict__ feats, const double* __restrict__ rnorm,
                      const float* __restrict__ sism, bf16* __restrict__ NFT,
                      double* __restrict__ vpp) {
  __shared__ float T[32][33];
  int n = blockIdx.z, k0 = blockIdx.x * 32, c0 = blockIdx.y * 32;
  int tx = threadIdx.x, ty = threadIdx.y;
  const float* fb = feats + ((size_t)n * KC + c0) * KHW + k0;
  {
    int tid = ty * 32 + tx;
    int cc = tid >> 3;          // 0..31
    int k4 = (tid & 7) * 4;     // 0..28
    float4 v = *(const float4*)&fb[(size_t)cc * KHW + k4];
    T[cc][k4 + 0] = v.x; T[cc][k4 + 1] = v.y;
    T[cc][k4 + 2] = v.z; T[cc][k4 + 3] = v.w;
  }
  __syncthreads();
  bf16* ob = NFT + ((size_t)n * KHW + k0) * KC + c0;
  #pragma unroll
  for (int ii = 0; ii < 4; ii++) {
    int kl = ty * 4 + ii;
    float r = (float)rnorm[n * KHW + k0 + kl];
    ob[(size_t)kl * KC + tx] = __float2bfloat16(T[tx][kl] * r);
  }
  double rs = rnorm[n * KHW + k0 + tx] * (double)sism[n * KHW + k0 + tx];
  #pragma unroll
  for (int ii = 0; ii < 4; ii++) {
    int cl = ty * 4 + ii;
    double v = (double)T[cl][tx] * rs;
    #pragma unroll
    for (int o = 16; o > 0; o >>= 1) v += __shfl_down(v, o, 32);
    if (tx == 0) vpp[((size_t)n * KC + c0 + cl) * 50 + k0 / 32] = v;
  }
}

__global__ void k_sivnorm2(const double* __restrict__ vpp, double* __restrict__ SIV) {
  int n = blockIdx.x, c = threadIdx.x;   // 512 threads
  const double* p = vpp + ((size_t)n * KC + c) * 50;
  double acc = 0;
  #pragma unroll 5
  for (int j = 0; j < 50; j++) acc += p[j];
  acc /= (double)KHW;
  double s2 = blockReduceSumD(acc * acc);
  double nn = sqrt(s2);
  if (nn < 1e-12) nn = 1e-12;
  SIV[n * KC + c] = acc / nn;
}

// 16 channel-slices of 32: 1120 blocks
__global__ void k_cmP(const float* __restrict__ feats, const double* __restrict__ SIV,
                      double* __restrict__ cmp) {
  __shared__ double sv[KN][32];
  int kc = blockIdx.x, ci = blockIdx.y, n = blockIdx.z;
  for (int t = threadIdx.x; t < KN * 32; t += 256) {
    int m = t / 32, c = t % 32;
    sv[m][c] = SIV[m * KC + ci * 32 + c];
  }
  __syncthreads();
  int k = kc * 256 + threadIdx.x;
  if (k >= KHW) return;
  const float* f = feats + ((size_t)n * KC + ci * 32) * KHW + k;
  double acc[KN];
  #pragma unroll
  for (int m = 0; m < KN; m++) acc[m] = 0.0;
  for (int c = 0; c < 32; ++c) {
    double fv = f[(size_t)c * KHW];
    #pragma unroll
    for (int m = 0; m < KN; m++) acc[m] += fv * sv[m][c];
  }
  const size_t str = (size_t)KN * KN * KHW;
  #pragma unroll
  for (int m = 0; m < KN; m++)
    cmp[(size_t)ci * str + ((size_t)n * KN + m) * KHW + k] = acc[m];
}

// fused cmB + cmnorm
__global__ void k_cmBN(const double* __restrict__ cmp, const double* __restrict__ rnorm,
                       double* __restrict__ cm) {
  int b = blockIdx.x;                       // 100 = n*KN + m
  int n = b / KN;
  const size_t str = (size_t)KN * KN * KHW;
  const size_t rb = (size_t)b * KHW;
  double v[4];
  int cnt = 0;
  double ss = 0;
  for (int k = threadIdx.x; k < KHW; k += 512) {
    double s = 0;
    #pragma unroll
    for (int ci = 0; ci < 16; ci++) s += cmp[ci * str + rb + k];
    s *= rnorm[n * KHW + k];
    v[cnt++] = s;
    ss += s * s;
  }
  ss = blockReduceSumD(ss);
  double nn = sqrt(ss);
  if (nn < 1e-12) nn = 1e-12;
  double rn = 1.0 / nn;
  cnt = 0;
  for (int k = threadIdx.x; k < KHW; k += 512) cm[rb + k] = v[cnt++] * rn;
}

__global__ void k_st(const double* __restrict__ cm, double* __restrict__ tbuf) {
  int b = blockIdx.x;
  int n = b / KN, m = b % KN;
  const double* base = cm + (size_t)n * KN * KHW;
  double acc = 0;
  for (int k = threadIdx.x; k < KHW; k += 256) {
    double S = 0;
    #pragma unroll
    for (int mm = 0; mm < KN; mm++) S += base[(size_t)mm * KHW + k];
    acc += base[(size_t)m * KHW + k] * S;
  }
  acc = blockReduceSumD(acc);
  if (threadIdx.x == 0) tbuf[b] = acc;
}

__global__ void k_csa(const double* __restrict__ cm, const double* __restrict__ tbuf,
                      double* __restrict__ CSAd, float* __restrict__ CSAf) {
  __shared__ double w[KN];
  int n = blockIdx.x, tid = threadIdx.x;
  if (tid == 0) {
    double v[KN], mx = -1e300;
    #pragma unroll
    for (int m = 0; m < KN; m++) { v[m] = tbuf[n * KN + m]; mx = fmax(mx, v[m]); }
    double s = 0;
    #pragma unroll
    for (int m = 0; m < KN; m++) { v[m] = exp(v[m] - mx); s += v[m]; }
    #pragma unroll
    for (int m = 0; m < KN; m++) w[m] = v[m] / s;
  }
  __syncthreads();
  double v[7];
  int cnt = 0;
  double lmin = 1e300, lmax = -1e300;
  for (int k = tid; k < KHW; k += 256) {
    double a = 0;
    #pragma unroll
    for (int m = 0; m < KN; m++) a += cm[((size_t)n * KN + m) * KHW + k] * w[m];
    v[cnt++] = a;
    lmin = fmin(lmin, a);
    lmax = fmax(lmax, a);
  }
  double mn = blockReduceMinD(lmin);
  double mx = blockReduceMaxD(lmax);
  double inv = 1.0 / (mx - mn + 1e-12);
  cnt = 0;
  for (int k = tid; k < KHW; k += 256) {
    double nv = (v[cnt++] - mn) * inv;
    CSAd[(size_t)n * KHW + k] = nv;
    CSAf[(size_t)n * KHW + k] = (float)nv;
  }
}

// rank-based stable descending argsort: idx[rank[i]] = i
__global__ void k_rank(const double* __restrict__ CSAd, int* __restrict__ idx) {
  __shared__ double key[KHW];
  int b = blockIdx.x;
  int n = b / 100, it = b % 100;
  const double* src = CSAd + (size_t)n * KHW;
  for (int j = threadIdx.x; j < KHW; j += 256) key[j] = src[j];
  __syncthreads();
  int wave = threadIdx.x >> 6, lane = threadIdx.x & 63;
  int i0 = it * 16 + wave * 4;
  double ki[4];
  #pragma unroll
  for (int ii = 0; ii < 4; ii++) ki[ii] = key[i0 + ii];
  int r[4] = {0, 0, 0, 0};
  #pragma unroll
  for (int q = 0; q < 25; q++) {
    int j = q * 64 + lane;
    double kj = key[j];
    #pragma unroll
    for (int ii = 0; ii < 4; ii++) {
      int i = i0 + ii;
      r[ii] += (kj > ki[ii]) || (kj == ki[ii] && j < i);
    }
  }
  #pragma unroll
  for (int ii = 0; ii < 4; ii++) {
    int v = r[ii];
    #pragma unroll
    for (int o = 32; o > 0; o >>= 1) v += __shfl_down(v, o);
    if (lane == 0) idx[n * KHW + v] = i0 + ii;
  }
}

// ---------------- fused input prep: w1s stack + w2 repack + pad borders ----------------
// blocks [0,8000): prepw1s; [8000,8576): prepw2; [8576,9089): zborder. All input-only.
__global__ void k_prep(const float* __restrict__ w1, const float* __restrict__ wsc,
                       const float* __restrict__ w2,
                       bf16* __restrict__ w1s, bf16* __restrict__ w2p,
                       bf16* __restrict__ Zpad, bf16* __restrict__ hpadT) {
  int b = blockIdx.x;
  if (b < 8000) {
    int t = b * 256 + threadIdx.x;           // over KM*KHW
    int m = t / KHW, i = t % KHW;
    int tau = m >> 7, o = m & 127;
    float v = (tau < 9) ? w1[((size_t)o * KHW + i) * 9 + tau]
                        : wsc[(size_t)o * KHW + i];
    w1s[t] = __float2bfloat16(v);
  } else if (b < 8576) {
    int t = (b - 8000) * 256 + threadIdx.x;
    if (t >= KOC * 9 * KOC) return;
    int o = t / (9 * KOC), r = t % (9 * KOC);
    int s = r / KOC, i = r % KOC;
    w2p[t] = __float2bfloat16(w2[(size_t)o * 9 * KOC + (size_t)i * 9 + s]);
  } else {
    int t = (b - 8576) * 256 + threadIdx.x;
    const int ZW = KN * 164 * (KC / 8);      // 104960
    const int HWm = KN * 164 * (KOC / 8);    // 26240
    int bb;
    if (t < ZW) {
      int n = t / (164 * 64), r = t % (164 * 64);
      bb = r / 64;
      int c8 = r % 64;
      int y, x;
      if (bb < 42) { y = 0; x = bb; }
      else if (bb < 84) { y = 41; x = bb - 42; }
      else if (bb < 124) { y = bb - 84 + 1; x = 0; }
      else { y = bb - 124 + 1; x = 41; }
      short8 z = {};
      *(short8*)((short*)Zpad + ((size_t)n * KPW * KPW + (size_t)y * KPW + x) * KC + c8 * 8) = z;
    } else if (t < ZW + HWm) {
      int u = t - ZW;
      int n = u / (164 * 16), r = u % (164 * 16);
      bb = r / 16;
      int c8 = r % 16;
      int y, x;
      if (bb < 42) { y = 0; x = bb; }
      else if (bb < 84) { y = 41; x = bb - 42; }
      else if (bb < 124) { y = bb - 84 + 1; x = 0; }
      else { y = bb - 124 + 1; x = 41; }
      short8 z = {};
      *(short8*)((short*)hpadT + ((size_t)n * KPW * KPW + (size_t)y * KPW + x) * KOC + c8 * 8) = z;
    }
  }
}

// ---------------- fused gather + Zpad prep (both consume NFT after rank; independent) -----
// blocks [0,8000): gath2 (NFcg); [8000,16000): zprep (Zpad). blockDim (32,8).
__global__ void k_gz(const short* __restrict__ NFT, const int* __restrict__ idx,
                     const float* __restrict__ CSAf,
                     short* __restrict__ NFcg, bf16* __restrict__ Zpad) {
  __shared__ short T[32][33];
  int b = blockIdx.x;
  int tx = threadIdx.x, ty = threadIdx.y;
  if (b < 8000) {
    int n = b / 800, r = b % 800;
    int c0 = (r / 50) * 32, i0 = (r % 50) * 32;
    #pragma unroll
    for (int ii = 0; ii < 4; ii++) {
      int row = ty * 4 + ii;
      int id = idx[n * KHW + i0 + row];
      T[row][tx] = NFT[((size_t)n * KHW + id) * KC + c0 + tx];
    }
    __syncthreads();
    #pragma unroll
    for (int ii = 0; ii < 4; ii++) {
      int cl = ty * 4 + ii;
      NFcg[((size_t)n * KC + c0 + cl) * KHW + i0 + tx] = T[tx][cl];
    }
  } else {
    int t = (b - 8000) * 256 + (ty * 32 + tx);   // over KN*KHW*KC/4
    const int per_n = KHW * (KC / 4);
    int n = t / per_n, r = t % per_n;
    int p = r / (KC / 4), cq = r % (KC / 4);
    float cs = CSAf[n * KHW + p];
    const short* src = (const short*)(NFT + ((size_t)n * KHW + p) * KC) + cq * 4;
    short4v v = *(const short4v*)src;
    short4v o;
    #pragma unroll
    for (int j = 0; j < 4; j++) {
      short s = v[j];
      bf16 hb = *reinterpret_cast<bf16*>(&s);
      bf16 res = __float2bfloat16(__bfloat162float(hb) * cs);
      o[j] = *reinterpret_cast<short*>(&res);
    }
    int y = p / KH, x = p % KH;
    short* dst = (short*)(Zpad + ((size_t)n * KPW * KPW + (size_t)(y + 1) * KPW + (x + 1)) * KC) + cq * 4;
    *(short4v*)dst = o;
  }
}

// ---------------- GEMM1: U = w1s x NFcg; 512-thread M=128xN=128 tile, BK=64 pipelined ------
// 400 blocks = 10 tau * 4 c0 * 10 n; XCD swizzle (400 % 8 == 0). LDS 64KB -> 2 blocks/CU
// -> 512 slots >= 400 -> single round, 16 waves/CU. Single-__syncthreads protocol.
__global__ __launch_bounds__(512) void k_gemmU(const short* __restrict__ w1s,
                                               const short* __restrict__ NFcg,
                                               bf16* __restrict__ Uc,
                                               bf16* __restrict__ Usc) {
  __shared__ __align__(16) short smem[32768];  // As[2][8192] | Bs[2][8192] (64 KB); reused as Cs[128][136]
  short* As = smem;                            // bufs at 0, 8192 (shorts)
  short* Bs = smem + 16384;                    // bufs at 16384, 24576
  short* Cs = smem;
  int b = blockIdx.x;
  int workid = (b & 7) * 50 + (b >> 3);        // bijective, 400 % 8 == 0
  int pair = workid / 10;                      // 0..39 : (n, c0 tile)
  int tau = workid % 10;
  int n = pair >> 2, c0 = (pair & 3) * 128;
  int m0 = tau * 128;
  int tid = threadIdx.x, lane = tid & 63, wave = tid >> 6;
  int quad = lane >> 4, l15 = lane & 15;
  int wm = (wave & 3) * 32, wn = (wave >> 2) * 64;
  int sk = ((tid & 7) ^ ((tid >> 3) & 7)) * 8; // pre-swizzled 16B-chunk (shorts); tid>>3 = row%64, &7 = row%8
  int rowg = tid >> 3;                          // 0..63
  const short* Bb = NFcg + (size_t)n * KC * KHW;
  const short* pA[2];
  #pragma unroll
  for (int g = 0; g < 2; g++)
    pA[g] = w1s + (size_t)(m0 + g * 64 + rowg) * KHW + sk;
  const short* pB[2];
  #pragma unroll
  for (int g = 0; g < 2; g++)
    pB[g] = Bb + (size_t)(c0 + g * 64 + rowg) * KHW + sk;
  char* lA = (char*)As + tid * 16;             // covers first 8KB (rows 0..63)
  char* lB = (char*)Bs + tid * 16;
  int bq = (l15 >> 2) & 1;
  int qx = (quad ^ (l15 & 3)) * 8;
  int koff0 = 32 * bq + qx;
  int koff1 = 32 * (1 - bq) + qx;
  f32x4 acc[2][4] = {};
  gload16(pA[0], lA); gload16(pA[1], lA + 8192);
  gload16(pB[0], lB); gload16(pB[1], lB + 8192);
  __syncthreads();                             // buf0 landed for all waves
  const int NS = 25;
  for (int s = 0; s < NS; s++) {
    int cb = s & 1, nb = cb ^ 1;
    if (s + 1 < NS) {
      int off = (s + 1) * 64;
      char* la = lA + nb * 16384;              // buf stride 16 KB
      char* lb = lB + nb * 16384;
      gload16(pA[0] + off, la); gload16(pA[1] + off, la + 8192);
      gload16(pB[0] + off, lb); gload16(pB[1] + off, lb + 8192);
    }
    const short* Ab = As + cb * 8192;
    const short* Bbf = Bs + cb * 8192;
    #pragma unroll
    for (int ks = 0; ks < 2; ks++) {
      int ko = (ks == 0) ? koff0 : koff1;
      short8 av[2], bv[4];
      #pragma unroll
      for (int t = 0; t < 2; t++) av[t] = *(const short8*)&Ab[(wm + t * 16 + l15) * 64 + ko];
      #pragma unroll
      for (int t = 0; t < 4; t++) bv[t] = *(const short8*)&Bbf[(wn + t * 16 + l15) * 64 + ko];
      #pragma unroll
      for (int ti = 0; ti < 2; ti++)
        #pragma unroll
        for (int tj = 0; tj < 4; tj++)
          acc[ti][tj] = __builtin_amdgcn_mfma_f32_16x16x32_bf16(av[ti], bv[tj], acc[ti][tj], 0, 0, 0);
    }
    __syncthreads();                           // drains prefetch; fences WAR on cb
  }
  // epilogue: bf16 transpose via Cs[128][136], then coalesced store
  #pragma unroll
  for (int ti = 0; ti < 2; ti++) {
    int lr = wm + ti * 16 + quad * 4;
    #pragma unroll
    for (int tj = 0; tj < 4; tj++) {
      int lc = wn + tj * 16 + l15;
      #pragma unroll
      for (int r = 0; r < 4; r++)
        *(bf16*)&Cs[(lr + r) * 136 + lc] = __float2bfloat16(acc[ti][tj][r]);
    }
  }
  __syncthreads();
  int dyq = tau / 3, dxq = tau % 3;
  #pragma unroll
  for (int pass = 0; pass < 4; pass++) {
    int row = pass * 32 + (tid >> 4);          // 0..127
    int col = (tid & 15) * 8;                  // 0..127
    if (tau < 9) {
      *(float4*)&Uc[((size_t)((n * 3 + dyq) * 128 + row)) * 1536 + dxq * 512 + c0 + col] =
          *(const float4*)&Cs[row * 136 + col];
    } else {
      *(float4*)&Usc[((size_t)(n * 128 + row)) * 512 + c0 + col] =
          *(const float4*)&Cs[row * 136 + col];
    }
  }
}

// ---------------- convh: dy-split pipelined GEMM, single-__syncthreads protocol ----------
// 1000 blocks: conv (long, NS=24) at blockIdx 0..749 (bijective m204 swizzle over 750),
// shortcut (short, NS=8) at 750..999 so the straggler round consists of SHORT blocks.
__global__ __launch_bounds__(256) void k_convh(const short* __restrict__ Uc,
                                               const short* __restrict__ Usc,
                                               const short* __restrict__ Zpad,
                                               float* __restrict__ Hpart) {
  __shared__ __align__(16) short smem[24576];  // As[2][8192] | Bs[2][4096]  (48 KB)
  short* As = smem;
  short* Bs = smem + 16384;
  int b = blockIdx.x;
  bool isconv = (b < 750);
  int n, dy, pt;
  if (isconv) {
    int xcd = b & 7, bi = b >> 3;
    int wgid = (xcd < 6 ? xcd * 94 : 6 * 94 + (xcd - 6) * 93) + bi;   // bijective over 750
    n = wgid / 75;
    int rest = wgid % 75;
    dy = rest / 25; pt = rest % 25;
  } else {
    int u = b - 750;
    n = u / 25; pt = u % 25; dy = 3;
  }
  int p0 = pt * 64;
  int tid = threadIdx.x, lane = tid & 63, wave = tid >> 6;
  int quad = lane >> 4, l15 = lane & 15;
  int wm = (wave & 1) * 64, wn = (wave >> 1) * 32;
  int sk = ((tid & 7) ^ ((tid >> 3) & 7)) * 8;
  int rowg = tid >> 3;
  const short* Zb = Zpad + (size_t)n * KPW * KPW * KC;
  const short* Abase = isconv ? Uc + ((size_t)((n * 3 + dy) * 128)) * 1536
                              : Usc + ((size_t)(n * 128)) * 512;
  int astr = isconv ? 1536 : 512;
  const short* pA[4];
  #pragma unroll
  for (int g = 0; g < 4; g++)
    pA[g] = Abase + (size_t)(g * 32 + rowg) * astr + sk;
  const short* pB[2];
  #pragma unroll
  for (int g = 0; g < 2; g++) {
    int p = p0 + g * 32 + rowg;
    int y = p / KH, x = p % KH;
    int yy = isconv ? (y + dy) : (y + 1);
    int xx = isconv ? x : (x + 1);
    pB[g] = Zb + ((size_t)yy * KPW + xx) * KC + sk;
  }
  char* lA = (char*)As + tid * 16;
  char* lB = (char*)Bs + tid * 16;
  int NS = isconv ? 24 : 8;
  int bq = (l15 >> 2) & 1;
  int qx = (quad ^ (l15 & 3)) * 8;
  int koff0 = 32 * bq + qx;
  int koff1 = 32 * (1 - bq) + qx;
  f32x4 acc[4][2] = {};
  gload16(pA[0], lA); gload16(pA[1], lA + 4096);
  gload16(pA[2], lA + 8192); gload16(pA[3], lA + 12288);
  gload16(pB[0], lB); gload16(pB[1], lB + 4096);
  __syncthreads();                             // buf0 landed
  for (int s = 0; s < NS; s++) {
    int cb = s & 1, nb = cb ^ 1;
    if (s + 1 < NS) {
      int off = (s + 1) * 64;
      char* la = lA + nb * 16384;
      char* lb = lB + nb * 8192;
      gload16(pA[0] + off, la); gload16(pA[1] + off, la + 4096);
      gload16(pA[2] + off, la + 8192); gload16(pA[3] + off, la + 12288);
      gload16(pB[0] + off, lb); gload16(pB[1] + off, lb + 4096);
    }
    const short* Ab = As + cb * 8192;
    const short* Bb = Bs + cb * 4096;
    #pragma unroll
    for (int ks = 0; ks < 2; ks++) {
      int ko = (ks == 0) ? koff0 : koff1;
      short8 av[4], bv[2];
      #pragma unroll
      for (int t = 0; t < 4; t++) av[t] = *(const short8*)&Ab[(wm + t * 16 + l15) * 64 + ko];
      #pragma unroll
      for (int t = 0; t < 2; t++) bv[t] = *(const short8*)&Bb[(wn + t * 16 + l15) * 64 + ko];
      #pragma unroll
      for (int ti = 0; ti < 4; ti++)
        #pragma unroll
        for (int tj = 0; tj < 2; tj++)
          acc[ti][tj] = __builtin_amdgcn_mfma_f32_16x16x32_bf16(av[ti], bv[tj], acc[ti][tj], 0, 0, 0);
    }
    __syncthreads();                           // drains prefetch; fences WAR on cb
  }
  float* cbp = Hpart + ((size_t)(dy * KN + n)) * KOC * KHW;
  #pragma unroll
  for (int ti = 0; ti < 4; ti++) {
    int o = wm + ti * 16 + quad * 4;
    #pragma unroll
    for (int tj = 0; tj < 2; tj++) {
      int q = p0 + wn + tj * 16 + l15;
      #pragma unroll
      for (int r = 0; r < 4; r++)
        cbp[(size_t)(o + r) * KHW + q] = acc[ti][tj][r];
    }
  }
}

// hpadT[n, y+1, x+1, o] = bf16(relu(b1[o] + Hpart[0]+Hpart[1]+Hpart[2]))
__global__ void k_hprep3(const float* __restrict__ Hpart, const float* __restrict__ b1,
                         bf16* __restrict__ hpadT) {
  __shared__ float T[32][132];
  int n = blockIdx.y, p0 = blockIdx.x * 32;
  int tx = threadIdx.x, ty = threadIdx.y;
  const size_t str = (size_t)KN * KOC * KHW;
  const float* hb = Hpart + (size_t)n * KOC * KHW;
  #pragma unroll
  for (int oc = 0; oc < 16; oc++) {
    int o = oc * 8 + ty;
    size_t off = (size_t)o * KHW + p0 + tx;
    T[tx][o] = fmaxf(hb[off] + hb[str + off] + hb[2 * str + off] + b1[o], 0.0f);
  }
  __syncthreads();
  bf16* hp = hpadT + (size_t)n * KPW * KPW * KOC;
  #pragma unroll
  for (int pc = 0; pc < 4; pc++) {
    int pl = ty * 4 + pc;
    int pp = p0 + pl;
    int yy = pp / KH, xx = pp % KH;
    bf16* row = hp + ((size_t)(yy + 1) * KPW + (xx + 1)) * KOC;
    #pragma unroll
    for (int u = 0; u < 4; u++) row[tx * 4 + u] = __float2bfloat16(T[pl][tx * 4 + u]);
  }
}

// ---------------- conv2f: dy-fused conv2 (K=1152) + bias + shortcut + relu -> out ----------
// 500 blocks = 10n * 50pt (N=32), m204 bijective XCD swizzle (500 = 8*62+4).
// LDS 40KB -> 4 blocks/CU = 1024 slots >= 500 -> single round. Single-__syncthreads protocol.
__global__ __launch_bounds__(256) void k_conv2f(const short* __restrict__ w2p,
                                                const short* __restrict__ hpadT,
                                                const float* __restrict__ Hpart,
                                                const float* __restrict__ b2,
                                                const float* __restrict__ bs,
                                                float* __restrict__ out) {
  __shared__ __align__(16) short smem[20480];  // As[2][8192] | Bs[2][2048] (40 KB)
  short* As = smem;
  short* Bs = smem + 16384;
  int b = blockIdx.x;
  int xcd = b & 7, bi = b >> 3;
  int wgid = (xcd < 4 ? xcd * 63 : 4 * 63 + (xcd - 4) * 62) + bi;   // bijective over 500
  int n = wgid / 50, pt = wgid % 50;
  int p0 = pt * 32;
  int tid = threadIdx.x, lane = tid & 63, wave = tid >> 6;
  int quad = lane >> 4, l15 = lane & 15;
  int wm = (wave & 1) * 64, wn = (wave >> 1) * 16;
  int sk = ((tid & 7) ^ ((tid >> 3) & 7)) * 8;
  int rowg = tid >> 3;                          // 0..31
  const short* hb = hpadT + (size_t)n * KPW * KPW * KOC;
  const short* pA[4];
  #pragma unroll
  for (int g = 0; g < 4; g++)
    pA[g] = w2p + (size_t)(g * 32 + rowg) * (9 * KOC) + sk;
  int prow = p0 + rowg;
  int py = prow / KH, px = prow % KH;
  const short* pB0 = hb + ((size_t)py * KPW + px) * KOC + sk;
  char* lA = (char*)As + tid * 16;
  char* lB = (char*)Bs + tid * 16;
  int bq = (l15 >> 2) & 1;
  int qx = (quad ^ (l15 & 3)) * 8;
  int koff0 = 32 * bq + qx;
  int koff1 = 32 * (1 - bq) + qx;
  f32x4 acc[4] = {};
  const int NS = 18;                            // 3dy * 3dx * (128/64); dy=s/6, dx=(s%6)>>1, kh=(s&1)*64
  gload16(pA[0], lA); gload16(pA[1], lA + 4096);
  gload16(pA[2], lA + 8192); gload16(pA[3], lA + 12288);
  gload16(pB0, lB);
  __syncthreads();                              // buf0 landed
  for (int s = 0; s < NS; s++) {
    int cb = s & 1, nb = cb ^ 1;
    if (s + 1 < NS) {
      int s2 = s + 1;
      int dy = s2 / 6, dxq = (s2 % 6) >> 1, kh = (s2 & 1) * 64;
      int ao = (dy * 3 + dxq) * 128 + kh;
      int bo = (dy * 42 + dxq) * 128 + kh;
      char* la = lA + nb * 16384;               // As buf stride 16 KB
      char* lb = lB + nb * 4096;                // Bs buf stride 4 KB
      gload16(pA[0] + ao, la); gload16(pA[1] + ao, la + 4096);
      gload16(pA[2] + ao, la + 8192); gload16(pA[3] + ao, la + 12288);
      gload16(pB0 + bo, lb);
    }
    const short* Ab = As + cb * 8192;
    const short* Bb = Bs + cb * 2048;
    #pragma unroll
    for (int ks = 0; ks < 2; ks++) {
      int ko = (ks == 0) ? koff0 : koff1;
      short8 av[4], bv;
      #pragma unroll
      for (int t = 0; t < 4; t++) av[t] = *(const short8*)&Ab[(wm + t * 16 + l15) * 64 + ko];
      bv = *(const short8*)&Bb[(wn + l15) * 64 + ko];
      #pragma unroll
      for (int ti = 0; ti < 4; ti++)
        acc[ti] = __builtin_amdgcn_mfma_f32_16x16x32_bf16(av[ti], bv, acc[ti], 0, 0, 0);
    }
    __syncthreads();                            // drains prefetch; fences WAR on cb
  }
  // epilogue: out = relu(acc + b2 + bs + Hpart[3])
  const float* hsc = Hpart + ((size_t)(3 * KN + n)) * KOC * KHW;
  float* ob = out + (size_t)n * KOC * KHW;
  int q = p0 + wn + l15;
  #pragma unroll
  for (int ti = 0; ti < 4; ti++) {
    int o = wm + ti * 16 + quad * 4;
    f32x4 b2v = *(const f32x4*)&b2[o];
    f32x4 bsv = *(const f32x4*)&bs[o];
    #pragma unroll
    for (int r = 0; r < 4; r++) {
      float v = acc[ti][r] + b2v[r] + bsv[r] + hsc[(size_t)(o + r) * KHW + q];
      ob[(size_t)(o + r) * KHW + q] = fmaxf(v, 0.0f);
    }
  }
}

// ---------------- launch ----------------
extern "C" void kernel_launch(void* const* d_in, const int* in_sizes, int n_in,
                              void* d_out, int out_size, void* d_ws, size_t ws_size,
                              hipStream_t stream) {
  const float* feats = (const float*)d_in[0];
  const float* sisms = (const float*)d_in[1];
  const float* w1 = (const float*)d_in[2];
  const float* b1 = (const float*)d_in[3];
  const float* w2 = (const float*)d_in[4];
  const float* b2 = (const float*)d_in[5];
  const float* wsc = (const float*)d_in[6];
  const float* bsc = (const float*)d_in[7];
  float* out = (float*)d_out;

  char* w = (char*)d_ws;
  auto carve = [&](size_t bytes) -> void* {
    void* p = (void*)w;
    w += (bytes + 255) & ~(size_t)255;
    return p;
  };
  bf16* NFT   = (bf16*)carve((size_t)KN * KHW * KC * 2);          // 16.4 MB
  bf16* NFcg  = (bf16*)carve((size_t)KN * KC * KHW * 2);          // 16.4 MB
  bf16* Uc    = (bf16*)carve((size_t)KN * 3 * 128 * 1536 * 2);    // 11.8 MB
  bf16* Usc   = (bf16*)carve((size_t)KN * 128 * 512 * 2);         // 1.3 MB
  bf16* w1s   = (bf16*)carve((size_t)KM * KHW * 2);               // 4.1 MB
  bf16* Zpad  = (bf16*)carve((size_t)KN * KPW * KPW * KC * 2);    // 18.1 MB
  bf16* hpadT = (bf16*)carve((size_t)KN * KPW * KPW * KOC * 2);   // 4.5 MB
  float* Hpart = (float*)carve((size_t)4 * KN * KOC * KHW * 4);   // 32.8 MB
  bf16* w2p   = (bf16*)carve((size_t)KOC * 9 * KOC * 2);
  double* psbuf = (double*)carve((size_t)16 * KN * KHW * 8);      // 2.05 MB
  double* rnorm = (double*)carve((size_t)KN * KHW * 8);
  double* vpp   = (double*)carve((size_t)KN * KC * 50 * 8);       // 2.05 MB
  double* SIV   = (double*)carve((size_t)KN * KC * 8);
  double* cmp   = (double*)carve((size_t)16 * KN * KN * KHW * 8); // 20.5 MB
  double* cm    = (double*)carve((size_t)KN * KN * KHW * 8);
  double* tbuf  = (double*)carve((size_t)KN * KN * 8);
  double* CSAd  = (double*)carve((size_t)KN * KHW * 8);
  float* CSAf   = (float*)carve((size_t)KN * KHW * 4);
  int* idxb     = (int*)carve((size_t)KN * KHW * 4);

  k_prep<<<9089, 256, 0, stream>>>(w1, wsc, w2, w1s, w2p, Zpad, hpadT);

  k_rnormp<<<dim3(16, 16), 256, 0, stream>>>(feats, psbuf);
  k_rnormc<<<63, 256, 0, stream>>>(psbuf, rnorm);
  k_nft<<<dim3(50, 16, KN), dim3(32, 8), 0, stream>>>(feats, rnorm, sisms, NFT, vpp);
  k_sivnorm2<<<KN, 512, 0, stream>>>(vpp, SIV);
  k_cmP<<<dim3(7, 16, KN), 256, 0, stream>>>(feats, SIV, cmp);
  k_cmBN<<<KN * KN, 512, 0, stream>>>(cmp, rnorm, cm);
  k_st<<<KN * KN, 256, 0, stream>>>(cm, tbuf);
  k_csa<<<KN, 256, 0, stream>>>(cm, tbuf, CSAd, CSAf);
  k_rank<<<1000, 256, 0, stream>>>(CSAd, idxb);

  k_gz<<<16000, dim3(32, 8), 0, stream>>>((const short*)NFT, idxb, CSAf,
                                          (short*)NFcg, Zpad);

  k_gemmU<<<400, 512, 0, stream>>>((const short*)w1s, (const short*)NFcg, Uc, Usc);
  k_convh<<<1000, 256, 0, stream>>>((const short*)Uc, (const short*)Usc,
                                    (const short*)Zpad, Hpart);
  k_hprep3<<<dim3(50, KN), dim3(32, 8), 0, stream>>>(Hpart, b1, hpadT);
  k_conv2f<<<500, 256, 0, stream>>>((const short*)w2p, (const short*)hpadT,
                                    Hpart, b2, bsc, out);
}